// Round 2
// baseline (422.838 us; speedup 1.0000x reference)
//
#include <hip/hip_runtime.h>
#include <stdint.h>

#define PP 196            // 14*14
#define BP 6272           // 32*196

typedef _Float16 half_t;
typedef half_t half8v __attribute__((ext_vector_type(8)));
typedef half_t half2v __attribute__((ext_vector_type(2)));

// ---------------------------------------------------------------------------
// assign kernels (layers 1,2): nearest-centroid 4-bit indices, packed 8/u32.
// f32 SCREEN + f64 FIXUP (R7-proven): screen tracks best/second-best; iff any
// lane's gap < TAU the wave re-runs that codebook with the exact f64 formula.
// idx layout: idxp[cb/8][BP]
// ---------------------------------------------------------------------------

template <typename T>
__global__ __launch_bounds__(256) void assign_1x1(
    const T* __restrict__ in, const float* __restrict__ cents,
    uint32_t* __restrict__ idxp, int nchan) {
  __shared__ float  sf[8][16][4];     // screen rows (16 B, one b128)
  __shared__ double sd[8][16][6];     // [c2, c0..c3, pad]: 48 B rows
  const int chunk = blockIdx.y;
  const int t = threadIdx.x;
  for (int i = t; i < 512; i += 256) {
    float c = cents[(size_t)chunk * 512 + i];
    int cb = i >> 6, r = i & 63;      // r = k*4 + d
    sf[cb][r >> 2][r & 3] = c;
    sd[cb][r >> 2][1 + (r & 3)] = (double)c;
  }
  __syncthreads();
  if (t < 128) {
    int cb = t >> 4, k = t & 15;
    double s = 0.0;
#pragma unroll
    for (int d = 0; d < 4; d++) { double c = sd[cb][k][1 + d]; s += c * c; }
    sd[cb][k][0] = s;
  }
  __syncthreads();
  const int p = blockIdx.x * 256 + t;
  if (p >= BP) return;
  const unsigned b = (unsigned)p / 196u;
  const unsigned pr = (unsigned)p - b * 196u;
  const T* xb = in + ((size_t)b * nchan + chunk * 32) * PP + pr;
  T xr[32];
#pragma unroll
  for (int i = 0; i < 32; i++) xr[i] = xb[(size_t)i * PP];
  float xs2[32];
#pragma unroll
  for (int i = 0; i < 32; i++) xs2[i] = 2.f * (float)xr[i];
  uint32_t word = 0;
#pragma unroll 1
  for (int cb = 0; cb < 8; cb++) {
    float best = 1e30f, sec = 1e30f; int bi = 0;
#pragma unroll
    for (int k = 0; k < 16; k++) {
      const float4 c = *(const float4*)&sf[cb][k][0];
      float dist = c.x * (c.x - xs2[cb * 4 + 0]);
      dist = fmaf(c.y, c.y - xs2[cb * 4 + 1], dist);
      dist = fmaf(c.z, c.z - xs2[cb * 4 + 2], dist);
      dist = fmaf(c.w, c.w - xs2[cb * 4 + 3], dist);
      if (dist < best) { sec = best; best = dist; bi = k; }
      else sec = fminf(sec, dist);
    }
    if (__any(sec - best < 2e-4f)) {
      double xv[4];
#pragma unroll
      for (int d = 0; d < 4; d++) xv[d] = (double)xr[cb * 4 + d];
      double bb = 1e300; int bi64 = 0;
#pragma unroll
      for (int k = 0; k < 16; k++) {
        double dot = 0.0;
#pragma unroll
        for (int d = 0; d < 4; d++) dot = fma(xv[d], sd[cb][k][1 + d], dot);
        double dist = sd[cb][k][0] - 2.0 * dot;
        if (dist < bb) { bb = dist; bi64 = k; }   // strict <: first-min
      }
      bi = bi64;
    }
    word |= (uint32_t)bi << (4 * cb);
  }
  idxp[(size_t)chunk * BP + p] = word;
}

__global__ __launch_bounds__(256) void assign_3x3(
    const double* __restrict__ in, const float* __restrict__ cents,
    uint32_t* __restrict__ idxp) {
  __shared__ float  sf[8][16][12];    // [c2f, c0..c8, pad, pad]: 48 B rows
  __shared__ double sd[8][16][10];    // [c2, c0..c8]: 80 B rows
  const int chunk = blockIdx.y;
  const int c0g = chunk * 8;
  const int t = threadIdx.x;
  for (int i = t; i < 1152; i += 256) {
    int cb = i / 144, r = i - cb * 144;
    int k = r / 9, d = r - k * 9;
    float c = cents[(size_t)(c0g + cb) * 144 + k * 9 + d];
    sf[cb][k][1 + d] = c;
    sd[cb][k][1 + d] = (double)c;
  }
  __syncthreads();
  if (t < 128) {
    int cb = t >> 4, k = t & 15;
    double s = 0.0;
    float s32 = 0.f;
#pragma unroll
    for (int d = 0; d < 9; d++) {
      double c = sd[cb][k][1 + d]; s += c * c;
      float cf = sf[cb][k][1 + d]; s32 += cf * cf;
    }
    sd[cb][k][0] = s;
    sf[cb][k][0] = s32;
  }
  __syncthreads();
  const int p = blockIdx.x * 256 + t;
  if (p >= BP) return;
  const unsigned b = (unsigned)p / 196u;
  const unsigned pr = (unsigned)p - b * 196u;
  const int oh = pr / 14, ow = pr - oh * 14;
  uint32_t word = 0;
#pragma unroll 1
  for (int cb = 0; cb < 8; cb++) {
    const double* base = in + ((size_t)b * 256 + (c0g + cb)) * PP;
    double v64[9]; float v32[9];
#pragma unroll
    for (int r = 0; r < 3; r++) {
#pragma unroll
      for (int cc = 0; cc < 3; cc++) {
        int hh = oh + r - 1, ww = ow + cc - 1;
        bool ok = (hh >= 0) & (hh < 14) & (ww >= 0) & (ww < 14);
        double v = ok ? base[hh * 14 + ww] : 0.0;
        v64[r * 3 + cc] = v;
        v32[r * 3 + cc] = (float)v;
      }
    }
    float best = 1e30f, sec = 1e30f; int bi = 0;
#pragma unroll
    for (int k = 0; k < 16; k++) {
      const float4 cA = *(const float4*)&sf[cb][k][0];  // c2f,c0,c1,c2
      const float4 cB = *(const float4*)&sf[cb][k][4];  // c3..c6
      const float4 cC = *(const float4*)&sf[cb][k][8];  // c7,c8,pad,pad
      float dot = v32[0] * cA.y;
      dot = fmaf(v32[1], cA.z, dot);
      dot = fmaf(v32[2], cA.w, dot);
      dot = fmaf(v32[3], cB.x, dot);
      dot = fmaf(v32[4], cB.y, dot);
      dot = fmaf(v32[5], cB.z, dot);
      dot = fmaf(v32[6], cB.w, dot);
      dot = fmaf(v32[7], cC.x, dot);
      dot = fmaf(v32[8], cC.y, dot);
      float dist = fmaf(-2.f, dot, cA.x);
      if (dist < best) { sec = best; best = dist; bi = k; }
      else sec = fminf(sec, dist);
    }
    if (__any(sec - best < 4e-4f)) {
      double bb = 1e300; int bi64 = 0;
#pragma unroll
      for (int k = 0; k < 16; k++) {
        double dot = 0.0;
#pragma unroll
        for (int d = 0; d < 9; d++) dot = fma(v64[d], sd[cb][k][1 + d], dot);
        double dist = sd[cb][k][0] - 2.0 * dot;
        if (dist < bb) { bb = dist; bi64 = k; }
      }
      bi = bi64;
    }
    word |= (uint32_t)bi << (4 * cb);
  }
  idxp[(size_t)chunk * BP + p] = word;
}

// ---------------------------------------------------------------------------
// accum v4 (f64-grade, reg-staged + T14 async split): out = act(scale *
// sum_cb lut[cb][idx][o] + bias) per (pos, 16 ch). 256-thread blocks (64 pos
// x 16 ch; q = wave = channel quad), grid (98, 16).
// Post-mortems: R0 (ds_write, 80B rows) = 48.6us, 3.24M write conflicts.
// R1 (global_load_lds DMA, 8-cb chunks) = 68.5us: conflicts -> 0 but the
// shallow prefetch (100-150cy compute vs 300-500cy DMA latency) + 64
// barriers exposed latency. v4 keeps R1's PROVEN conflict-free layout and
// fixes the schedule:
//  - TRANSPOSED linear slot layout: slot = cb*64 + q*16 + k (16B slots).
//    Writes: thread t writes slots t+256j -> lane-linear 16B granules,
//    conflict-free. Gathers: addr = cb*256 + q*64 + idx*4 floats -> per
//    bank-quad at most 2 distinct addresses (idx, idx+8) -> free (R1: ~0
//    conflicts measured).
//  - 16-cb chunks (R0 size), double-buffered 2 x 16 KB, ONE barrier per
//    chunk (16 total): write ch+1 (regs) -> issue loads ch+2 -> gather ch
//    (16 ds_read_b128 ~ 300cy, covers the ~200cy L2-hit load latency) ->
//    barrier. Buffer reuse distance = 2 chunks, so the single barrier
//    covers the WAR hazard.
// PAIRWISE accumulation: adjacent cb pairs summed in f32 (err ~7e-7 rms),
// then one cvt+f64 add per pair -- identical arithmetic order to v2/v3.
// FUSE3 (layer 2): epilogue computes the layer-3 assignment in-register.
// ---------------------------------------------------------------------------
template <int NCB, int NOUT, bool RELU, bool FUSE3, typename OutT>
__global__ __launch_bounds__(256) void accum_f64(
    const float* __restrict__ lut, const uint32_t* __restrict__ idxp,
    const float* __restrict__ scale, const float* __restrict__ bias,
    const float* __restrict__ c3cent, uint8_t* __restrict__ i3b,
    OutT* __restrict__ out) {
  __shared__ float s_lut[2 * 4096];   // 32 KB: 2 bufs x (16 cb x 16 k x 16 out)
  __shared__ float  c3f[4][16][4];
  __shared__ float  c3c2f[4][16];
  __shared__ double c3d[4][16][4];
  __shared__ double c3c2d[4][16];
  const int t = threadIdx.x;
  const int lane = t & 63;
  const int q = t >> 6;                 // channel quad 0..3 (wave id)
  const int p = blockIdx.x * 64 + lane; // 98*64 = 6272 = BP exactly
  const int o_base = blockIdx.y * 16;
  if (FUSE3 && t < 64) {
    int cb_l = t >> 4, k = t & 15;
    const float4 cf = *(const float4*)(c3cent + ((size_t)(blockIdx.y * 4 + cb_l)) * 64 + k * 4);
    c3f[cb_l][k][0] = cf.x; c3f[cb_l][k][1] = cf.y;
    c3f[cb_l][k][2] = cf.z; c3f[cb_l][k][3] = cf.w;
    double d0 = (double)cf.x, d1 = (double)cf.y, d2 = (double)cf.z, d3 = (double)cf.w;
    c3d[cb_l][k][0] = d0; c3d[cb_l][k][1] = d1;
    c3d[cb_l][k][2] = d2; c3d[cb_l][k][3] = d3;
    double s = 0.0; s += d0 * d0; s += d1 * d1; s += d2 * d2; s += d3 * d3;
    c3c2d[cb_l][k] = s;
    float s32 = 0.f; s32 += cf.x * cf.x; s32 += cf.y * cf.y;
    s32 += cf.z * cf.z; s32 += cf.w * cf.w;
    c3c2f[cb_l][k] = s32;
  }

  // Slot s (of 1024/chunk) -> (cb = s>>6, q_s = (s>>4)&3, k = s&15);
  // LDS float-offset = s*4; global row = (ch*16 + cb)*16 + k, col q_s*4.
  // Thread t owns slots t + 256j, j=0..3  (cb = (t>>6) + 4j).
  const float* src0 = lut + ((size_t)(t >> 6) * 16 + (t & 15)) * NOUT
                          + o_base + ((t >> 4) & 3) * 4;
  constexpr int NCHUNK = NCB / 16;                 // 16
  constexpr size_t CSTRIDE = (size_t)256 * NOUT;   // 16 cb * 16 k rows / chunk
  float4 rj[4];
  // prologue: load chunk 0 -> regs -> buf0; load chunk 1 -> regs
#pragma unroll
  for (int j = 0; j < 4; j++)
    rj[j] = *(const float4*)(src0 + (size_t)(64 * j) * NOUT);
#pragma unroll
  for (int j = 0; j < 4; j++)
    *(float4*)(s_lut + (t + 256 * j) * 4) = rj[j];
#pragma unroll
  for (int j = 0; j < 4; j++)
    rj[j] = *(const float4*)(src0 + CSTRIDE + (size_t)(64 * j) * NOUT);
  uint32_t w0 = idxp[p];
  uint32_t w1 = idxp[(size_t)BP + p];
  __syncthreads();   // buf0 + c3 tables published

  double a0 = 0, a1 = 0, a2 = 0, a3 = 0;
#pragma unroll 1
  for (int ch = 0; ch < NCHUNK; ch++) {
    const uint32_t cw0 = w0, cw1 = w1;
    // write chunk ch+1 (staged regs) into the other buffer
    if (ch + 1 < NCHUNK) {
      float* d = s_lut + ((ch + 1) & 1) * 4096;
#pragma unroll
      for (int j = 0; j < 4; j++)
        *(float4*)(d + (t + 256 * j) * 4) = rj[j];
    }
    // issue loads for chunk ch+2 + idx words for ch+1 (consumed next iter)
    if (ch + 2 < NCHUNK) {
      const float* s = src0 + (size_t)(ch + 2) * CSTRIDE;
#pragma unroll
      for (int j = 0; j < 4; j++)
        rj[j] = *(const float4*)(s + (size_t)(64 * j) * NOUT);
    }
    if (ch + 1 < NCHUNK) {
      w0 = idxp[(size_t)(2 * ch + 2) * BP + p];
      w1 = idxp[(size_t)(2 * ch + 3) * BP + p];
    }
    // gather chunk ch
    const float* buf = s_lut + (ch & 1) * 4096 + q * 64;
#pragma unroll
    for (int j = 0; j < 8; j++) {        // cb pair (2j, 2j+1) within chunk
      uint32_t w = (j < 4) ? cw0 : cw1;
      int sh = (j & 3) * 8;
      int i0 = (int)((w >> sh) & 15u);
      int i1 = (int)((w >> (sh + 4)) & 15u);
      const float4 va = *(const float4*)(buf + (2 * j) * 256 + i0 * 4);
      const float4 vb = *(const float4*)(buf + (2 * j + 1) * 256 + i1 * 4);
      float s0 = va.x + vb.x, s1 = va.y + vb.y;
      float s2 = va.z + vb.z, s3 = va.w + vb.w;
      a0 += (double)s0; a1 += (double)s1; a2 += (double)s2; a3 += (double)s3;
    }
    __syncthreads();   // gathers of ch done before writes of ch+2 (reuse dist 2)
  }
  const unsigned b = (unsigned)p / 196u;
  const unsigned pr = (unsigned)p - b * 196u;
  const int o = o_base + q * 4;
  const float4 sc = *(const float4*)(scale + o);
  const float4 bs = *(const float4*)(bias + o);
  double r0 = a0 * (double)sc.x + (double)bs.x;
  double r1 = a1 * (double)sc.y + (double)bs.y;
  double r2 = a2 * (double)sc.z + (double)bs.z;
  double r3 = a3 * (double)sc.w + (double)bs.w;
  if (RELU) {
    r0 = fmax(r0, 0.0); r1 = fmax(r1, 0.0);
    r2 = fmax(r2, 0.0); r3 = fmax(r3, 0.0);
  }
  if (FUSE3) {
    // layer-3 assignment for codebook cb3 = blockIdx.y*4 + q (this thread's 4 ch)
    const int cb_l = q;
    float x0 = (float)r0, x1 = (float)r1, x2 = (float)r2, x3 = (float)r3;
    float best = 1e30f, sec = 1e30f; int bi = 0;
#pragma unroll
    for (int k = 0; k < 16; k++) {
      const float4 c = *(const float4*)&c3f[cb_l][k][0];
      float dot = x0 * c.x;
      dot = fmaf(x1, c.y, dot);
      dot = fmaf(x2, c.z, dot);
      dot = fmaf(x3, c.w, dot);
      float dist = fmaf(-2.f, dot, c3c2f[cb_l][k]);
      if (dist < best) { sec = best; best = dist; bi = k; }
      else sec = fminf(sec, dist);
    }
    if (__any(sec - best < 1e-3f)) {
      double bb = 1e300; int bi64 = 0;
#pragma unroll
      for (int k = 0; k < 16; k++) {
        double dot = 0.0;
        dot = fma(r0, c3d[cb_l][k][0], dot);
        dot = fma(r1, c3d[cb_l][k][1], dot);
        dot = fma(r2, c3d[cb_l][k][2], dot);
        dot = fma(r3, c3d[cb_l][k][3], dot);
        double dist = c3c2d[cb_l][k] - 2.0 * dot;
        if (dist < bb) { bb = dist; bi64 = k; }   // strict <: first-min
      }
      bi = bi64;
    }
    i3b[(size_t)p * 64 + blockIdx.y * 4 + q] = (uint8_t)bi;
  } else {
    OutT* op = out + ((size_t)b * NOUT + o) * PP + pr;
    op[0 * PP] = (OutT)r0; op[1 * PP] = (OutT)r1;
    op[2 * PP] = (OutT)r2; op[3 * PP] = (OutT)r3;
  }
}

// ---------------------------------------------------------------------------
// accum3: final layer (no downstream argmin). f32 LUT -> f16 staged in-register;
// packed v_pk_add_f16 inner loop, partials flushed to f32 every 8 codebooks.
// Index read: one dwordx4 of bytes per chunk from i3b[p][cb]. Rows 40 halfs
// (80 B): bank-quad (5*idx+h)%8 bijective -> 2-way = free.
// grid (49, 64), block 256 (4 waves): 128 positions x 16 channels.
// ---------------------------------------------------------------------------
__global__ __launch_bounds__(256) void accum3_f16(
    const float* __restrict__ lut, const uint8_t* __restrict__ i3b,
    const float* __restrict__ scale, const float* __restrict__ bias,
    const float* __restrict__ res, float* __restrict__ out) {
  __shared__ half_t s16[16 * 640];   // 20 KB
  const int t = threadIdx.x;
  const int lane = t & 63;
  const int wave = t >> 6;           // 0..3
  const int h = wave & 1;            // channel half (8 f16 ch)
  const int pg = wave >> 1;          // 0..1
  const int p = blockIdx.x * 128 + pg * 64 + lane;
  const int o_base = blockIdx.y * 16;
  // staging slots s0=t, s1=t+256 of 512: (cb=s>>5, k=(s>>1)&15, hh=s&1)
  const int s0 = t, s1 = t + 256;
  const int cA = s0 >> 5, kA = (s0 >> 1) & 15, hA = s0 & 1;
  const int cB = s1 >> 5, kB = (s1 >> 1) & 15, hB = s1 & 1;
  const size_t cs = (size_t)16 * 16 * 1024;     // 16 cb per chunk (f32 elems)
  constexpr int NCHUNK = 4;
  float acc[8];
#pragma unroll
  for (int i = 0; i < 8; i++) acc[i] = 0.f;
  for (int ch = 0; ch < NCHUNK; ch++) {
    __syncthreads();
    const uint4 iw = *(const uint4*)(i3b + (size_t)p * 64 + ch * 16);
    {
      const float* gA = lut + (size_t)ch * cs + ((size_t)cA * 16 + kA) * 1024 + o_base + hA * 8;
      const float* gB = lut + (size_t)ch * cs + ((size_t)cB * 16 + kB) * 1024 + o_base + hB * 8;
      float4 a0 = *(const float4*)gA;
      float4 a1 = *(const float4*)(gA + 4);
      float4 b0 = *(const float4*)gB;
      float4 b1 = *(const float4*)(gB + 4);
      half8v va, vb;
      va[0] = (half_t)a0.x; va[1] = (half_t)a0.y; va[2] = (half_t)a0.z; va[3] = (half_t)a0.w;
      va[4] = (half_t)a1.x; va[5] = (half_t)a1.y; va[6] = (half_t)a1.z; va[7] = (half_t)a1.w;
      vb[0] = (half_t)b0.x; vb[1] = (half_t)b0.y; vb[2] = (half_t)b0.z; vb[3] = (half_t)b0.w;
      vb[4] = (half_t)b1.x; vb[5] = (half_t)b1.y; vb[6] = (half_t)b1.z; vb[7] = (half_t)b1.w;
      *(half8v*)(s16 + cA * 640 + kA * 40 + hA * 8) = va;
      *(half8v*)(s16 + cB * 640 + kB * 40 + hB * 8) = vb;
    }
    __syncthreads();
#pragma unroll
    for (int grp = 0; grp < 2; grp++) {   // 8 cb per f32 flush
      uint32_t wa = grp ? iw.z : iw.x;
      uint32_t wb = grp ? iw.w : iw.y;
      half2v p0 = 0, p1 = 0, p2 = 0, p3 = 0;
#pragma unroll
      for (int j = 0; j < 8; j++) {
        uint32_t w = (j < 4) ? wa : wb;
        int idx = (int)((w >> ((j & 3) * 8)) & 15u);
        int cb_l = grp * 8 + j;
        const half8v v = *(const half8v*)(s16 + cb_l * 640 + idx * 40 + h * 8);
        const half2v* vp = (const half2v*)&v;
        p0 += vp[0]; p1 += vp[1]; p2 += vp[2]; p3 += vp[3];
      }
      acc[0] += (float)p0[0]; acc[1] += (float)p0[1];
      acc[2] += (float)p1[0]; acc[3] += (float)p1[1];
      acc[4] += (float)p2[0]; acc[5] += (float)p2[1];
      acc[6] += (float)p3[0]; acc[7] += (float)p3[1];
    }
  }
  const unsigned b = (unsigned)p / 196u;
  const unsigned pr = (unsigned)p - b * 196u;
  const int o = o_base + h * 8;
  const float* rp = res + ((size_t)b * 1024 + o) * PP + pr;
  float* op = out + ((size_t)b * 1024 + o) * PP + pr;
#pragma unroll
  for (int i = 0; i < 8; i++) {
    float v = acc[i] * scale[o + i] + bias[o + i] + rp[(size_t)i * PP];
    op[(size_t)i * PP] = fmaxf(v, 0.f);
  }
}

// ---------------------------------------------------------------------------

extern "C" void kernel_launch(void* const* d_in, const int* in_sizes, int n_in,
                              void* d_out, int out_size, void* d_ws, size_t ws_size,
                              hipStream_t stream) {
  const float* x   = (const float*)d_in[0];   // [32,1024,14,14]
  const float* c1c = (const float*)d_in[1];
  const float* c1l = (const float*)d_in[2];
  const float* c1s = (const float*)d_in[3];
  const float* c1b = (const float*)d_in[4];
  const float* c2c = (const float*)d_in[5];
  const float* c2l = (const float*)d_in[6];
  const float* c2s = (const float*)d_in[7];
  const float* c2b = (const float*)d_in[8];
  const float* c3c = (const float*)d_in[9];
  const float* c3l = (const float*)d_in[10];  // [64,16,1024]
  const float* c3s = (const float*)d_in[11];
  const float* c3b = (const float*)d_in[12];

  const size_t sz_i1  = (size_t)32 * BP * 4;      // 802,816 B
  const size_t sz_i2  = (size_t)32 * BP * 4;
  const size_t sz_i3b = (size_t)BP * 64;          // 401,408 B (byte indices)
  const size_t sz_o64 = (size_t)BP * 256 * 8;     // 12.85 MB

  char* w = (char*)d_ws;
  uint32_t* i1 = (uint32_t*)w; w += sz_i1;
  uint32_t* i2 = (uint32_t*)w; w += sz_i2;
  uint8_t* i3b = (uint8_t*)w;  w += sz_i3b;
  double* out1;
  if (ws_size >= (size_t)(w - (char*)d_ws) + sz_o64) {
    out1 = (double*)w;
  } else {
    // d_out (25.69 MB f32) holds one 12.85 MB f64 array in its first half;
    // accum3 (final) reads only i3b/x/c3l, then overwrites all of d_out.
    out1 = (double*)d_out;
  }

  const dim3 blkA(256), blkC(256);
  // layer 1: 1x1, 256 codebooks (dsub=4) over 1024 input channels
  assign_1x1<float><<<dim3(25, 32), blkA, 0, stream>>>(x, c1c, i1, 1024);
  accum_f64<256, 256, true, false, double><<<dim3(98, 16), blkC, 0, stream>>>(
      c1l, i1, c1s, c1b, nullptr, nullptr, out1);
  // layer 2: 3x3, 256 codebooks (dsub=9); epilogue fuses the layer-3 assign
  assign_3x3<<<dim3(25, 32), blkA, 0, stream>>>(out1, c2c, i2);
  accum_f64<256, 256, true, true, double><<<dim3(98, 16), blkC, 0, stream>>>(
      c2l, i2, c2s, c2b, c3c, i3b, nullptr);
  // layer 3: 64 codebooks over 256 channels; fused residual + relu
  accum3_f16<<<dim3(49, 64), blkC, 0, stream>>>(
      c3l, i3b, c3s, c3b, x, (float*)d_out);
}

// Round 3
// 272.380 us; speedup vs baseline: 1.5524x; 1.5524x over previous
//
#include <hip/hip_runtime.h>
#include <stdint.h>

#define PP 196            // 14*14
#define BP 6272           // 32*196

typedef _Float16 half_t;
typedef half_t half8v __attribute__((ext_vector_type(8)));
typedef half_t half2v __attribute__((ext_vector_type(2)));

// ---------------------------------------------------------------------------
// assign kernels (layers 1,2): nearest-centroid 4-bit indices, packed 8/u32.
// f32 SCREEN + f64 FIXUP (R7-proven): screen tracks best/second-best; iff any
// lane's gap < TAU the wave re-runs that codebook with the exact f64 formula.
// idx layout: idxp[cb/8][BP]
// ---------------------------------------------------------------------------

template <typename T>
__global__ __launch_bounds__(256) void assign_1x1(
    const T* __restrict__ in, const float* __restrict__ cents,
    uint32_t* __restrict__ idxp, int nchan) {
  __shared__ float  sf[8][16][4];     // screen rows (16 B, one b128)
  __shared__ double sd[8][16][6];     // [c2, c0..c3, pad]: 48 B rows
  const int chunk = blockIdx.y;
  const int t = threadIdx.x;
  for (int i = t; i < 512; i += 256) {
    float c = cents[(size_t)chunk * 512 + i];
    int cb = i >> 6, r = i & 63;      // r = k*4 + d
    sf[cb][r >> 2][r & 3] = c;
    sd[cb][r >> 2][1 + (r & 3)] = (double)c;
  }
  __syncthreads();
  if (t < 128) {
    int cb = t >> 4, k = t & 15;
    double s = 0.0;
#pragma unroll
    for (int d = 0; d < 4; d++) { double c = sd[cb][k][1 + d]; s += c * c; }
    sd[cb][k][0] = s;
  }
  __syncthreads();
  const int p = blockIdx.x * 256 + t;
  if (p >= BP) return;
  const unsigned b = (unsigned)p / 196u;
  const unsigned pr = (unsigned)p - b * 196u;
  const T* xb = in + ((size_t)b * nchan + chunk * 32) * PP + pr;
  T xr[32];
#pragma unroll
  for (int i = 0; i < 32; i++) xr[i] = xb[(size_t)i * PP];
  float xs2[32];
#pragma unroll
  for (int i = 0; i < 32; i++) xs2[i] = 2.f * (float)xr[i];
  uint32_t word = 0;
#pragma unroll 1
  for (int cb = 0; cb < 8; cb++) {
    float best = 1e30f, sec = 1e30f; int bi = 0;
#pragma unroll
    for (int k = 0; k < 16; k++) {
      const float4 c = *(const float4*)&sf[cb][k][0];
      float dist = c.x * (c.x - xs2[cb * 4 + 0]);
      dist = fmaf(c.y, c.y - xs2[cb * 4 + 1], dist);
      dist = fmaf(c.z, c.z - xs2[cb * 4 + 2], dist);
      dist = fmaf(c.w, c.w - xs2[cb * 4 + 3], dist);
      if (dist < best) { sec = best; best = dist; bi = k; }
      else sec = fminf(sec, dist);
    }
    if (__any(sec - best < 2e-4f)) {
      double xv[4];
#pragma unroll
      for (int d = 0; d < 4; d++) xv[d] = (double)xr[cb * 4 + d];
      double bb = 1e300; int bi64 = 0;
#pragma unroll
      for (int k = 0; k < 16; k++) {
        double dot = 0.0;
#pragma unroll
        for (int d = 0; d < 4; d++) dot = fma(xv[d], sd[cb][k][1 + d], dot);
        double dist = sd[cb][k][0] - 2.0 * dot;
        if (dist < bb) { bb = dist; bi64 = k; }   // strict <: first-min
      }
      bi = bi64;
    }
    word |= (uint32_t)bi << (4 * cb);
  }
  idxp[(size_t)chunk * BP + p] = word;
}

__global__ __launch_bounds__(256) void assign_3x3(
    const double* __restrict__ in, const float* __restrict__ cents,
    uint32_t* __restrict__ idxp) {
  __shared__ float  sf[8][16][12];    // [c2f, c0..c8, pad, pad]: 48 B rows
  __shared__ double sd[8][16][10];    // [c2, c0..c8]: 80 B rows
  const int chunk = blockIdx.y;
  const int c0g = chunk * 8;
  const int t = threadIdx.x;
  for (int i = t; i < 1152; i += 256) {
    int cb = i / 144, r = i - cb * 144;
    int k = r / 9, d = r - k * 9;
    float c = cents[(size_t)(c0g + cb) * 144 + k * 9 + d];
    sf[cb][k][1 + d] = c;
    sd[cb][k][1 + d] = (double)c;
  }
  __syncthreads();
  if (t < 128) {
    int cb = t >> 4, k = t & 15;
    double s = 0.0;
    float s32 = 0.f;
#pragma unroll
    for (int d = 0; d < 9; d++) {
      double c = sd[cb][k][1 + d]; s += c * c;
      float cf = sf[cb][k][1 + d]; s32 += cf * cf;
    }
    sd[cb][k][0] = s;
    sf[cb][k][0] = s32;
  }
  __syncthreads();
  const int p = blockIdx.x * 256 + t;
  if (p >= BP) return;
  const unsigned b = (unsigned)p / 196u;
  const unsigned pr = (unsigned)p - b * 196u;
  const int oh = pr / 14, ow = pr - oh * 14;
  uint32_t word = 0;
#pragma unroll 1
  for (int cb = 0; cb < 8; cb++) {
    const double* base = in + ((size_t)b * 256 + (c0g + cb)) * PP;
    double v64[9]; float v32[9];
#pragma unroll
    for (int r = 0; r < 3; r++) {
#pragma unroll
      for (int cc = 0; cc < 3; cc++) {
        int hh = oh + r - 1, ww = ow + cc - 1;
        bool ok = (hh >= 0) & (hh < 14) & (ww >= 0) & (ww < 14);
        double v = ok ? base[hh * 14 + ww] : 0.0;
        v64[r * 3 + cc] = v;
        v32[r * 3 + cc] = (float)v;
      }
    }
    float best = 1e30f, sec = 1e30f; int bi = 0;
#pragma unroll
    for (int k = 0; k < 16; k++) {
      const float4 cA = *(const float4*)&sf[cb][k][0];  // c2f,c0,c1,c2
      const float4 cB = *(const float4*)&sf[cb][k][4];  // c3..c6
      const float4 cC = *(const float4*)&sf[cb][k][8];  // c7,c8,pad,pad
      float dot = v32[0] * cA.y;
      dot = fmaf(v32[1], cA.z, dot);
      dot = fmaf(v32[2], cA.w, dot);
      dot = fmaf(v32[3], cB.x, dot);
      dot = fmaf(v32[4], cB.y, dot);
      dot = fmaf(v32[5], cB.z, dot);
      dot = fmaf(v32[6], cB.w, dot);
      dot = fmaf(v32[7], cC.x, dot);
      dot = fmaf(v32[8], cC.y, dot);
      float dist = fmaf(-2.f, dot, cA.x);
      if (dist < best) { sec = best; best = dist; bi = k; }
      else sec = fminf(sec, dist);
    }
    if (__any(sec - best < 4e-4f)) {
      double bb = 1e300; int bi64 = 0;
#pragma unroll
      for (int k = 0; k < 16; k++) {
        double dot = 0.0;
#pragma unroll
        for (int d = 0; d < 9; d++) dot = fma(v64[d], sd[cb][k][1 + d], dot);
        double dist = sd[cb][k][0] - 2.0 * dot;
        if (dist < bb) { bb = dist; bi64 = k; }
      }
      bi = bi64;
    }
    word |= (uint32_t)bi << (4 * cb);
  }
  idxp[(size_t)chunk * BP + p] = word;
}

// ---------------------------------------------------------------------------
// accum v5 (f64-grade): R0's PROVEN schedule (16-cb chunks, load->ds_write->
// barrier->gather->barrier, no cross-iteration register state) with the
// TRANSPOSED conflict-free LDS layout proven in R1/R2 (0 conflicts measured):
//   slot s = cb*64 + q_s*16 + k, float-offset s*4 (16B slots, no padding).
//   Staging: thread t writes slots t+256j (j=0..3) -> per wave a contiguous
//   1KB lane-linear span = 2 lanes/bank-quad = free (m136). Source row for
//   slot: lut row (ch*256 + cb*16 + k), cols o_base+q_s*4 .. +3.
//   Gather: float4 at cb*256 + q*64 + idx*4; lanes differ only in idx ->
//   bank-quads hold (idx, idx+8) -> <=2 distinct addrs = free.
// Post-mortems driving this: R0 48.6us (3.24M WRITE-side conflicts, 80B-row
// layout); R1 DMA dbuf 68.5us (latency-exposed, conflicts 0); R2 reg-prefetch
// 145us (rj[4] spilled: WRITE_SIZE 1.6MB->133MB). Cross-iteration staging
// loses either way; single-iteration staging + TLP (~6 blocks/CU) hides
// load latency fine (R0 proved it at 48.6 with WORSE LDS traffic).
// PAIRWISE accumulation: adjacent cb pairs summed in f32 (err ~7e-7 rms),
// then one cvt+f64 add per pair -- identical arithmetic order to v2.
// FUSE3 (layer 2): epilogue computes the layer-3 assignment in-register.
// ---------------------------------------------------------------------------
template <int NCB, int NOUT, bool RELU, bool FUSE3, typename OutT>
__global__ __launch_bounds__(256) void accum_f64(
    const float* __restrict__ lut, const uint32_t* __restrict__ idxp,
    const float* __restrict__ scale, const float* __restrict__ bias,
    const float* __restrict__ c3cent, uint8_t* __restrict__ i3b,
    OutT* __restrict__ out) {
  __shared__ float s_lut[4096];       // 16 KB: 16 cb x 16 k x 16 out
  __shared__ float  c3f[4][16][4];
  __shared__ float  c3c2f[4][16];
  __shared__ double c3d[4][16][4];
  __shared__ double c3c2d[4][16];
  const int t = threadIdx.x;
  const int lane = t & 63;
  const int q = t >> 6;                 // channel quad 0..3 (wave id)
  const int p = blockIdx.x * 64 + lane; // 98*64 = 6272 = BP exactly
  const int o_base = blockIdx.y * 16;
  if (FUSE3 && t < 64) {
    int cb_l = t >> 4, k = t & 15;
    const float4 cf = *(const float4*)(c3cent + ((size_t)(blockIdx.y * 4 + cb_l)) * 64 + k * 4);
    c3f[cb_l][k][0] = cf.x; c3f[cb_l][k][1] = cf.y;
    c3f[cb_l][k][2] = cf.z; c3f[cb_l][k][3] = cf.w;
    double d0 = (double)cf.x, d1 = (double)cf.y, d2 = (double)cf.z, d3 = (double)cf.w;
    c3d[cb_l][k][0] = d0; c3d[cb_l][k][1] = d1;
    c3d[cb_l][k][2] = d2; c3d[cb_l][k][3] = d3;
    double s = 0.0; s += d0 * d0; s += d1 * d1; s += d2 * d2; s += d3 * d3;
    c3c2d[cb_l][k] = s;
    float s32 = 0.f; s32 += cf.x * cf.x; s32 += cf.y * cf.y;
    s32 += cf.z * cf.z; s32 += cf.w * cf.w;
    c3c2f[cb_l][k] = s32;
  }
  // staging source: thread t owns slots t+256j -> cb=(t>>6)+4j, q_s=(t>>4)&3,
  // k=t&15; global row (t>>6)*16+(t&15) + ch*256 + 64j, col o_base+q_s*4.
  const float* src = lut + ((size_t)(t >> 6) * 16 + (t & 15)) * NOUT
                         + o_base + ((t >> 4) & 3) * 4;
  double a0 = 0, a1 = 0, a2 = 0, a3 = 0;
  constexpr int NCHUNK = NCB / 16;
  for (int ch = 0; ch < NCHUNK; ch++) {
    __syncthreads();               // prior chunk's gathers done before overwrite
    uint32_t w0 = idxp[(size_t)(ch * 2) * BP + p];
    uint32_t w1 = idxp[(size_t)(ch * 2 + 1) * BP + p];
    {
      const float* g = src + (size_t)(ch * 256) * NOUT;
#pragma unroll
      for (int j = 0; j < 4; j++) {
        float4 v = *(const float4*)(g + (size_t)(64 * j) * NOUT);
        *(float4*)(s_lut + (t + 256 * j) * 4) = v;
      }
    }
    __syncthreads();               // chunk published
    const float* buf = s_lut + q * 64;
#pragma unroll
    for (int j = 0; j < 8; j++) {  // cb pair (2j, 2j+1)
      uint32_t w = (j < 4) ? w0 : w1;
      int sh = (j & 3) * 8;
      int i0 = (int)((w >> sh) & 15u);
      int i1 = (int)((w >> (sh + 4)) & 15u);
      const float4 va = *(const float4*)(buf + (2 * j) * 256 + i0 * 4);
      const float4 vb = *(const float4*)(buf + (2 * j + 1) * 256 + i1 * 4);
      float s0 = va.x + vb.x, s1 = va.y + vb.y;
      float s2 = va.z + vb.z, s3 = va.w + vb.w;
      a0 += (double)s0; a1 += (double)s1; a2 += (double)s2; a3 += (double)s3;
    }
  }
  const unsigned b = (unsigned)p / 196u;
  const unsigned pr = (unsigned)p - b * 196u;
  const int o = o_base + q * 4;
  const float4 sc = *(const float4*)(scale + o);
  const float4 bs = *(const float4*)(bias + o);
  double r0 = a0 * (double)sc.x + (double)bs.x;
  double r1 = a1 * (double)sc.y + (double)bs.y;
  double r2 = a2 * (double)sc.z + (double)bs.z;
  double r3 = a3 * (double)sc.w + (double)bs.w;
  if (RELU) {
    r0 = fmax(r0, 0.0); r1 = fmax(r1, 0.0);
    r2 = fmax(r2, 0.0); r3 = fmax(r3, 0.0);
  }
  if (FUSE3) {
    // layer-3 assignment for codebook cb3 = blockIdx.y*4 + q (this thread's 4 ch)
    const int cb_l = q;
    float x0 = (float)r0, x1 = (float)r1, x2 = (float)r2, x3 = (float)r3;
    float best = 1e30f, sec = 1e30f; int bi = 0;
#pragma unroll
    for (int k = 0; k < 16; k++) {
      const float4 c = *(const float4*)&c3f[cb_l][k][0];
      float dot = x0 * c.x;
      dot = fmaf(x1, c.y, dot);
      dot = fmaf(x2, c.z, dot);
      dot = fmaf(x3, c.w, dot);
      float dist = fmaf(-2.f, dot, c3c2f[cb_l][k]);
      if (dist < best) { sec = best; best = dist; bi = k; }
      else sec = fminf(sec, dist);
    }
    if (__any(sec - best < 1e-3f)) {
      double bb = 1e300; int bi64 = 0;
#pragma unroll
      for (int k = 0; k < 16; k++) {
        double dot = 0.0;
        dot = fma(r0, c3d[cb_l][k][0], dot);
        dot = fma(r1, c3d[cb_l][k][1], dot);
        dot = fma(r2, c3d[cb_l][k][2], dot);
        dot = fma(r3, c3d[cb_l][k][3], dot);
        double dist = c3c2d[cb_l][k] - 2.0 * dot;
        if (dist < bb) { bb = dist; bi64 = k; }   // strict <: first-min
      }
      bi = bi64;
    }
    i3b[(size_t)p * 64 + blockIdx.y * 4 + q] = (uint8_t)bi;
  } else {
    OutT* op = out + ((size_t)b * NOUT + o) * PP + pr;
    op[0 * PP] = (OutT)r0; op[1 * PP] = (OutT)r1;
    op[2 * PP] = (OutT)r2; op[3 * PP] = (OutT)r3;
  }
}

// ---------------------------------------------------------------------------
// accum3: final layer (no downstream argmin). f32 LUT -> f16 staged in-register;
// packed v_pk_add_f16 inner loop, partials flushed to f32 every 8 codebooks.
// Index read: one dwordx4 of bytes per chunk from i3b[p][cb]. Rows 40 halfs
// (80 B): bank-quad (5*idx+h)%8 bijective -> 2-way = free.
// grid (49, 64), block 256 (4 waves): 128 positions x 16 channels.
// ---------------------------------------------------------------------------
__global__ __launch_bounds__(256) void accum3_f16(
    const float* __restrict__ lut, const uint8_t* __restrict__ i3b,
    const float* __restrict__ scale, const float* __restrict__ bias,
    const float* __restrict__ res, float* __restrict__ out) {
  __shared__ half_t s16[16 * 640];   // 20 KB
  const int t = threadIdx.x;
  const int lane = t & 63;
  const int wave = t >> 6;           // 0..3
  const int h = wave & 1;            // channel half (8 f16 ch)
  const int pg = wave >> 1;          // 0..1
  const int p = blockIdx.x * 128 + pg * 64 + lane;
  const int o_base = blockIdx.y * 16;
  // staging slots s0=t, s1=t+256 of 512: (cb=s>>5, k=(s>>1)&15, hh=s&1)
  const int s0 = t, s1 = t + 256;
  const int cA = s0 >> 5, kA = (s0 >> 1) & 15, hA = s0 & 1;
  const int cB = s1 >> 5, kB = (s1 >> 1) & 15, hB = s1 & 1;
  const size_t cs = (size_t)16 * 16 * 1024;     // 16 cb per chunk (f32 elems)
  constexpr int NCHUNK = 4;
  float acc[8];
#pragma unroll
  for (int i = 0; i < 8; i++) acc[i] = 0.f;
  for (int ch = 0; ch < NCHUNK; ch++) {
    __syncthreads();
    const uint4 iw = *(const uint4*)(i3b + (size_t)p * 64 + ch * 16);
    {
      const float* gA = lut + (size_t)ch * cs + ((size_t)cA * 16 + kA) * 1024 + o_base + hA * 8;
      const float* gB = lut + (size_t)ch * cs + ((size_t)cB * 16 + kB) * 1024 + o_base + hB * 8;
      float4 a0 = *(const float4*)gA;
      float4 a1 = *(const float4*)(gA + 4);
      float4 b0 = *(const float4*)gB;
      float4 b1 = *(const float4*)(gB + 4);
      half8v va, vb;
      va[0] = (half_t)a0.x; va[1] = (half_t)a0.y; va[2] = (half_t)a0.z; va[3] = (half_t)a0.w;
      va[4] = (half_t)a1.x; va[5] = (half_t)a1.y; va[6] = (half_t)a1.z; va[7] = (half_t)a1.w;
      vb[0] = (half_t)b0.x; vb[1] = (half_t)b0.y; vb[2] = (half_t)b0.z; vb[3] = (half_t)b0.w;
      vb[4] = (half_t)b1.x; vb[5] = (half_t)b1.y; vb[6] = (half_t)b1.z; vb[7] = (half_t)b1.w;
      *(half8v*)(s16 + cA * 640 + kA * 40 + hA * 8) = va;
      *(half8v*)(s16 + cB * 640 + kB * 40 + hB * 8) = vb;
    }
    __syncthreads();
#pragma unroll
    for (int grp = 0; grp < 2; grp++) {   // 8 cb per f32 flush
      uint32_t wa = grp ? iw.z : iw.x;
      uint32_t wb = grp ? iw.w : iw.y;
      half2v p0 = 0, p1 = 0, p2 = 0, p3 = 0;
#pragma unroll
      for (int j = 0; j < 8; j++) {
        uint32_t w = (j < 4) ? wa : wb;
        int idx = (int)((w >> ((j & 3) * 8)) & 15u);
        int cb_l = grp * 8 + j;
        const half8v v = *(const half8v*)(s16 + cb_l * 640 + idx * 40 + h * 8);
        const half2v* vp = (const half2v*)&v;
        p0 += vp[0]; p1 += vp[1]; p2 += vp[2]; p3 += vp[3];
      }
      acc[0] += (float)p0[0]; acc[1] += (float)p0[1];
      acc[2] += (float)p1[0]; acc[3] += (float)p1[1];
      acc[4] += (float)p2[0]; acc[5] += (float)p2[1];
      acc[6] += (float)p3[0]; acc[7] += (float)p3[1];
    }
  }
  const unsigned b = (unsigned)p / 196u;
  const unsigned pr = (unsigned)p - b * 196u;
  const int o = o_base + h * 8;
  const float* rp = res + ((size_t)b * 1024 + o) * PP + pr;
  float* op = out + ((size_t)b * 1024 + o) * PP + pr;
#pragma unroll
  for (int i = 0; i < 8; i++) {
    float v = acc[i] * scale[o + i] + bias[o + i] + rp[(size_t)i * PP];
    op[(size_t)i * PP] = fmaxf(v, 0.f);
  }
}

// ---------------------------------------------------------------------------

extern "C" void kernel_launch(void* const* d_in, const int* in_sizes, int n_in,
                              void* d_out, int out_size, void* d_ws, size_t ws_size,
                              hipStream_t stream) {
  const float* x   = (const float*)d_in[0];   // [32,1024,14,14]
  const float* c1c = (const float*)d_in[1];
  const float* c1l = (const float*)d_in[2];
  const float* c1s = (const float*)d_in[3];
  const float* c1b = (const float*)d_in[4];
  const float* c2c = (const float*)d_in[5];
  const float* c2l = (const float*)d_in[6];
  const float* c2s = (const float*)d_in[7];
  const float* c2b = (const float*)d_in[8];
  const float* c3c = (const float*)d_in[9];
  const float* c3l = (const float*)d_in[10];  // [64,16,1024]
  const float* c3s = (const float*)d_in[11];
  const float* c3b = (const float*)d_in[12];

  const size_t sz_i1  = (size_t)32 * BP * 4;      // 802,816 B
  const size_t sz_i2  = (size_t)32 * BP * 4;
  const size_t sz_i3b = (size_t)BP * 64;          // 401,408 B (byte indices)
  const size_t sz_o64 = (size_t)BP * 256 * 8;     // 12.85 MB

  char* w = (char*)d_ws;
  uint32_t* i1 = (uint32_t*)w; w += sz_i1;
  uint32_t* i2 = (uint32_t*)w; w += sz_i2;
  uint8_t* i3b = (uint8_t*)w;  w += sz_i3b;
  double* out1;
  if (ws_size >= (size_t)(w - (char*)d_ws) + sz_o64) {
    out1 = (double*)w;
  } else {
    // d_out (25.69 MB f32) holds one 12.85 MB f64 array in its first half;
    // accum3 (final) reads only i3b/x/c3l, then overwrites all of d_out.
    out1 = (double*)d_out;
  }

  const dim3 blkA(256), blkC(256);
  // layer 1: 1x1, 256 codebooks (dsub=4) over 1024 input channels
  assign_1x1<float><<<dim3(25, 32), blkA, 0, stream>>>(x, c1c, i1, 1024);
  accum_f64<256, 256, true, false, double><<<dim3(98, 16), blkC, 0, stream>>>(
      c1l, i1, c1s, c1b, nullptr, nullptr, out1);
  // layer 2: 3x3, 256 codebooks (dsub=9); epilogue fuses the layer-3 assign
  assign_3x3<<<dim3(25, 32), blkA, 0, stream>>>(out1, c2c, i2);
  accum_f64<256, 256, true, true, double><<<dim3(98, 16), blkC, 0, stream>>>(
      c2l, i2, c2s, c2b, c3c, i3b, nullptr);
  // layer 3: 64 codebooks over 256 channels; fused residual + relu
  accum3_f16<<<dim3(49, 64), blkC, 0, stream>>>(
      c3l, i3b, c3s, c3b, x, (float*)d_out);
}

// Round 4
// 251.839 us; speedup vs baseline: 1.6790x; 1.0816x over previous
//
#include <hip/hip_runtime.h>
#include <stdint.h>

#define PP 196            // 14*14
#define BP 6272           // 32*196

typedef _Float16 half_t;
typedef half_t half8v __attribute__((ext_vector_type(8)));
typedef half_t half2v __attribute__((ext_vector_type(2)));

// ---------------------------------------------------------------------------
// assign kernels (layers 1,2): nearest-centroid 4-bit indices, packed 8/u32.
// f32 SCREEN + f64 FIXUP (R7-proven): screen tracks best/second-best; iff any
// lane's gap < TAU the wave re-runs that codebook with the exact f64 formula.
// idx layout: idxp[cb/8][BP]
// ---------------------------------------------------------------------------

template <typename T>
__global__ __launch_bounds__(256) void assign_1x1(
    const T* __restrict__ in, const float* __restrict__ cents,
    uint32_t* __restrict__ idxp, int nchan) {
  __shared__ float  sf[8][16][4];     // screen rows (16 B, one b128)
  __shared__ double sd[8][16][6];     // [c2, c0..c3, pad]: 48 B rows
  const int chunk = blockIdx.y;
  const int t = threadIdx.x;
  for (int i = t; i < 512; i += 256) {
    float c = cents[(size_t)chunk * 512 + i];
    int cb = i >> 6, r = i & 63;      // r = k*4 + d
    sf[cb][r >> 2][r & 3] = c;
    sd[cb][r >> 2][1 + (r & 3)] = (double)c;
  }
  __syncthreads();
  if (t < 128) {
    int cb = t >> 4, k = t & 15;
    double s = 0.0;
#pragma unroll
    for (int d = 0; d < 4; d++) { double c = sd[cb][k][1 + d]; s += c * c; }
    sd[cb][k][0] = s;
  }
  __syncthreads();
  const int p = blockIdx.x * 256 + t;
  if (p >= BP) return;
  const unsigned b = (unsigned)p / 196u;
  const unsigned pr = (unsigned)p - b * 196u;
  const T* xb = in + ((size_t)b * nchan + chunk * 32) * PP + pr;
  T xr[32];
#pragma unroll
  for (int i = 0; i < 32; i++) xr[i] = xb[(size_t)i * PP];
  float xs2[32];
#pragma unroll
  for (int i = 0; i < 32; i++) xs2[i] = 2.f * (float)xr[i];
  uint32_t word = 0;
#pragma unroll 1
  for (int cb = 0; cb < 8; cb++) {
    float best = 1e30f, sec = 1e30f; int bi = 0;
#pragma unroll
    for (int k = 0; k < 16; k++) {
      const float4 c = *(const float4*)&sf[cb][k][0];
      float dist = c.x * (c.x - xs2[cb * 4 + 0]);
      dist = fmaf(c.y, c.y - xs2[cb * 4 + 1], dist);
      dist = fmaf(c.z, c.z - xs2[cb * 4 + 2], dist);
      dist = fmaf(c.w, c.w - xs2[cb * 4 + 3], dist);
      if (dist < best) { sec = best; best = dist; bi = k; }
      else sec = fminf(sec, dist);
    }
    if (__any(sec - best < 2e-4f)) {
      double xv[4];
#pragma unroll
      for (int d = 0; d < 4; d++) xv[d] = (double)xr[cb * 4 + d];
      double bb = 1e300; int bi64 = 0;
#pragma unroll
      for (int k = 0; k < 16; k++) {
        double dot = 0.0;
#pragma unroll
        for (int d = 0; d < 4; d++) dot = fma(xv[d], sd[cb][k][1 + d], dot);
        double dist = sd[cb][k][0] - 2.0 * dot;
        if (dist < bb) { bb = dist; bi64 = k; }   // strict <: first-min
      }
      bi = bi64;
    }
    word |= (uint32_t)bi << (4 * cb);
  }
  idxp[(size_t)chunk * BP + p] = word;
}

__global__ __launch_bounds__(256) void assign_3x3(
    const double* __restrict__ in, const float* __restrict__ cents,
    uint32_t* __restrict__ idxp) {
  __shared__ float  sf[8][16][12];    // [c2f, c0..c8, pad, pad]: 48 B rows
  __shared__ double sd[8][16][10];    // [c2, c0..c8]: 80 B rows
  const int chunk = blockIdx.y;
  const int c0g = chunk * 8;
  const int t = threadIdx.x;
  for (int i = t; i < 1152; i += 256) {
    int cb = i / 144, r = i - cb * 144;
    int k = r / 9, d = r - k * 9;
    float c = cents[(size_t)(c0g + cb) * 144 + k * 9 + d];
    sf[cb][k][1 + d] = c;
    sd[cb][k][1 + d] = (double)c;
  }
  __syncthreads();
  if (t < 128) {
    int cb = t >> 4, k = t & 15;
    double s = 0.0;
    float s32 = 0.f;
#pragma unroll
    for (int d = 0; d < 9; d++) {
      double c = sd[cb][k][1 + d]; s += c * c;
      float cf = sf[cb][k][1 + d]; s32 += cf * cf;
    }
    sd[cb][k][0] = s;
    sf[cb][k][0] = s32;
  }
  __syncthreads();
  const int p = blockIdx.x * 256 + t;
  if (p >= BP) return;
  const unsigned b = (unsigned)p / 196u;
  const unsigned pr = (unsigned)p - b * 196u;
  const int oh = pr / 14, ow = pr - oh * 14;
  uint32_t word = 0;
#pragma unroll 1
  for (int cb = 0; cb < 8; cb++) {
    const double* base = in + ((size_t)b * 256 + (c0g + cb)) * PP;
    double v64[9]; float v32[9];
#pragma unroll
    for (int r = 0; r < 3; r++) {
#pragma unroll
      for (int cc = 0; cc < 3; cc++) {
        int hh = oh + r - 1, ww = ow + cc - 1;
        bool ok = (hh >= 0) & (hh < 14) & (ww >= 0) & (ww < 14);
        double v = ok ? base[hh * 14 + ww] : 0.0;
        v64[r * 3 + cc] = v;
        v32[r * 3 + cc] = (float)v;
      }
    }
    float best = 1e30f, sec = 1e30f; int bi = 0;
#pragma unroll
    for (int k = 0; k < 16; k++) {
      const float4 cA = *(const float4*)&sf[cb][k][0];  // c2f,c0,c1,c2
      const float4 cB = *(const float4*)&sf[cb][k][4];  // c3..c6
      const float4 cC = *(const float4*)&sf[cb][k][8];  // c7,c8,pad,pad
      float dot = v32[0] * cA.y;
      dot = fmaf(v32[1], cA.z, dot);
      dot = fmaf(v32[2], cA.w, dot);
      dot = fmaf(v32[3], cB.x, dot);
      dot = fmaf(v32[4], cB.y, dot);
      dot = fmaf(v32[5], cB.z, dot);
      dot = fmaf(v32[6], cB.w, dot);
      dot = fmaf(v32[7], cC.x, dot);
      dot = fmaf(v32[8], cC.y, dot);
      float dist = fmaf(-2.f, dot, cA.x);
      if (dist < best) { sec = best; best = dist; bi = k; }
      else sec = fminf(sec, dist);
    }
    if (__any(sec - best < 4e-4f)) {
      double bb = 1e300; int bi64 = 0;
#pragma unroll
      for (int k = 0; k < 16; k++) {
        double dot = 0.0;
#pragma unroll
        for (int d = 0; d < 9; d++) dot = fma(v64[d], sd[cb][k][1 + d], dot);
        double dist = sd[cb][k][0] - 2.0 * dot;
        if (dist < bb) { bb = dist; bi64 = k; }
      }
      bi = bi64;
    }
    word |= (uint32_t)bi << (4 * cb);
  }
  idxp[(size_t)chunk * BP + p] = word;
}

// ---------------------------------------------------------------------------
// accum v6 (f64-grade): R0's schedule + transposed conflict-free LDS layout +
// COALESCED staging ownership. The three rounds isolated the constraints:
//  - R0 (srow=t>>2 ownership, 80B rows): 48.6us, coalesced loads (4 lanes =
//    64B contiguous) but 3.24M write-side conflicts.
//  - R3 (k=t&15 ownership, linear slots): conflicts ~0 but consecutive lanes
//    stride 1024B in global -> 64 VMEM req/wave-load (4x R0) -> 65us, TA-bound
//    (~100K req-cycles/CU ~= 42us of pure request issue).
//  - v6: slot layout UNCHANGED (slot = cb*64 + q_s*16 + k; gather quad =
//    idx%8 -> <=2 addrs = free; proven R1/R3) but ownership permutation
//    sigma(t) = (t>>6)*64 + (t&3)*16 + ((t>>2)&15): thread t sources global
//    row (t>>6)*16 + ((t>>2)&15), col o_base+(t&3)*4 -> lanes 0-3 read 64
//    contiguous bytes of one row (R0's 16-req pattern); write quad = (t>>2)&7
//    -> uniform 8 lanes/quad, same distribution as lane-linear (measured ~0).
// PAIRWISE accumulation: adjacent cb pairs summed in f32 (err ~7e-7 rms),
// then one cvt+f64 add per pair -- identical arithmetic order to v2.
// FUSE3 (layer 2): epilogue computes the layer-3 assignment in-register.
// ---------------------------------------------------------------------------
template <int NCB, int NOUT, bool RELU, bool FUSE3, typename OutT>
__global__ __launch_bounds__(256) void accum_f64(
    const float* __restrict__ lut, const uint32_t* __restrict__ idxp,
    const float* __restrict__ scale, const float* __restrict__ bias,
    const float* __restrict__ c3cent, uint8_t* __restrict__ i3b,
    OutT* __restrict__ out) {
  __shared__ float s_lut[4096];       // 16 KB: 16 cb x 16 k x 16 out
  __shared__ float  c3f[4][16][4];
  __shared__ float  c3c2f[4][16];
  __shared__ double c3d[4][16][4];
  __shared__ double c3c2d[4][16];
  const int t = threadIdx.x;
  const int lane = t & 63;
  const int q = t >> 6;                 // channel quad 0..3 (wave id)
  const int p = blockIdx.x * 64 + lane; // 98*64 = 6272 = BP exactly
  const int o_base = blockIdx.y * 16;
  if (FUSE3 && t < 64) {
    int cb_l = t >> 4, k = t & 15;
    const float4 cf = *(const float4*)(c3cent + ((size_t)(blockIdx.y * 4 + cb_l)) * 64 + k * 4);
    c3f[cb_l][k][0] = cf.x; c3f[cb_l][k][1] = cf.y;
    c3f[cb_l][k][2] = cf.z; c3f[cb_l][k][3] = cf.w;
    double d0 = (double)cf.x, d1 = (double)cf.y, d2 = (double)cf.z, d3 = (double)cf.w;
    c3d[cb_l][k][0] = d0; c3d[cb_l][k][1] = d1;
    c3d[cb_l][k][2] = d2; c3d[cb_l][k][3] = d3;
    double s = 0.0; s += d0 * d0; s += d1 * d1; s += d2 * d2; s += d3 * d3;
    c3c2d[cb_l][k] = s;
    float s32 = 0.f; s32 += cf.x * cf.x; s32 += cf.y * cf.y;
    s32 += cf.z * cf.z; s32 += cf.w * cf.w;
    c3c2f[cb_l][k] = s32;
  }
  // staging ownership: thread t owns slots sigma(t)+256j, j=0..3 ->
  //   cb = (t>>6)+4j, q_s = t&3, k = (t>>2)&15.
  // global source: row (ch*256 + cb*16 + k), col o_base + q_s*4 -> 4
  // consecutive lanes cover 64 contiguous bytes of one LUT row (coalesced).
  const float* src = lut + ((size_t)(t >> 6) * 16 + ((t >> 2) & 15)) * NOUT
                         + o_base + (t & 3) * 4;
  const int sslot = (t >> 6) * 64 + (t & 3) * 16 + ((t >> 2) & 15);
  double a0 = 0, a1 = 0, a2 = 0, a3 = 0;
  constexpr int NCHUNK = NCB / 16;
  for (int ch = 0; ch < NCHUNK; ch++) {
    __syncthreads();               // prior chunk's gathers done before overwrite
    uint32_t w0 = idxp[(size_t)(ch * 2) * BP + p];
    uint32_t w1 = idxp[(size_t)(ch * 2 + 1) * BP + p];
    {
      const float* g = src + (size_t)(ch * 256) * NOUT;
#pragma unroll
      for (int j = 0; j < 4; j++) {
        float4 v = *(const float4*)(g + (size_t)(64 * j) * NOUT);
        *(float4*)(s_lut + (sslot + 256 * j) * 4) = v;
      }
    }
    __syncthreads();               // chunk published
    const float* buf = s_lut + q * 64;
#pragma unroll
    for (int j = 0; j < 8; j++) {  // cb pair (2j, 2j+1)
      uint32_t w = (j < 4) ? w0 : w1;
      int sh = (j & 3) * 8;
      int i0 = (int)((w >> sh) & 15u);
      int i1 = (int)((w >> (sh + 4)) & 15u);
      const float4 va = *(const float4*)(buf + (2 * j) * 256 + i0 * 4);
      const float4 vb = *(const float4*)(buf + (2 * j + 1) * 256 + i1 * 4);
      float s0 = va.x + vb.x, s1 = va.y + vb.y;
      float s2 = va.z + vb.z, s3 = va.w + vb.w;
      a0 += (double)s0; a1 += (double)s1; a2 += (double)s2; a3 += (double)s3;
    }
  }
  const unsigned b = (unsigned)p / 196u;
  const unsigned pr = (unsigned)p - b * 196u;
  const int o = o_base + q * 4;
  const float4 sc = *(const float4*)(scale + o);
  const float4 bs = *(const float4*)(bias + o);
  double r0 = a0 * (double)sc.x + (double)bs.x;
  double r1 = a1 * (double)sc.y + (double)bs.y;
  double r2 = a2 * (double)sc.z + (double)bs.z;
  double r3 = a3 * (double)sc.w + (double)bs.w;
  if (RELU) {
    r0 = fmax(r0, 0.0); r1 = fmax(r1, 0.0);
    r2 = fmax(r2, 0.0); r3 = fmax(r3, 0.0);
  }
  if (FUSE3) {
    // layer-3 assignment for codebook cb3 = blockIdx.y*4 + q (this thread's 4 ch)
    const int cb_l = q;
    float x0 = (float)r0, x1 = (float)r1, x2 = (float)r2, x3 = (float)r3;
    float best = 1e30f, sec = 1e30f; int bi = 0;
#pragma unroll
    for (int k = 0; k < 16; k++) {
      const float4 c = *(const float4*)&c3f[cb_l][k][0];
      float dot = x0 * c.x;
      dot = fmaf(x1, c.y, dot);
      dot = fmaf(x2, c.z, dot);
      dot = fmaf(x3, c.w, dot);
      float dist = fmaf(-2.f, dot, c3c2f[cb_l][k]);
      if (dist < best) { sec = best; best = dist; bi = k; }
      else sec = fminf(sec, dist);
    }
    if (__any(sec - best < 1e-3f)) {
      double bb = 1e300; int bi64 = 0;
#pragma unroll
      for (int k = 0; k < 16; k++) {
        double dot = 0.0;
        dot = fma(r0, c3d[cb_l][k][0], dot);
        dot = fma(r1, c3d[cb_l][k][1], dot);
        dot = fma(r2, c3d[cb_l][k][2], dot);
        dot = fma(r3, c3d[cb_l][k][3], dot);
        double dist = c3c2d[cb_l][k] - 2.0 * dot;
        if (dist < bb) { bb = dist; bi64 = k; }   // strict <: first-min
      }
      bi = bi64;
    }
    i3b[(size_t)p * 64 + blockIdx.y * 4 + q] = (uint8_t)bi;
  } else {
    OutT* op = out + ((size_t)b * NOUT + o) * PP + pr;
    op[0 * PP] = (OutT)r0; op[1 * PP] = (OutT)r1;
    op[2 * PP] = (OutT)r2; op[3 * PP] = (OutT)r3;
  }
}

// ---------------------------------------------------------------------------
// accum3: final layer (no downstream argmin). f32 LUT -> f16 staged in-register;
// packed v_pk_add_f16 inner loop, partials flushed to f32 every 8 codebooks.
// Index read: one dwordx4 of bytes per chunk from i3b[p][cb]. Rows 40 halfs
// (80 B): bank-quad (5*idx+h)%8 bijective -> 2-way = free.
// grid (49, 64), block 256 (4 waves): 128 positions x 16 channels.
// ---------------------------------------------------------------------------
__global__ __launch_bounds__(256) void accum3_f16(
    const float* __restrict__ lut, const uint8_t* __restrict__ i3b,
    const float* __restrict__ scale, const float* __restrict__ bias,
    const float* __restrict__ res, float* __restrict__ out) {
  __shared__ half_t s16[16 * 640];   // 20 KB
  const int t = threadIdx.x;
  const int lane = t & 63;
  const int wave = t >> 6;           // 0..3
  const int h = wave & 1;            // channel half (8 f16 ch)
  const int pg = wave >> 1;          // 0..1
  const int p = blockIdx.x * 128 + pg * 64 + lane;
  const int o_base = blockIdx.y * 16;
  // staging slots s0=t, s1=t+256 of 512: (cb=s>>5, k=(s>>1)&15, hh=s&1)
  const int s0 = t, s1 = t + 256;
  const int cA = s0 >> 5, kA = (s0 >> 1) & 15, hA = s0 & 1;
  const int cB = s1 >> 5, kB = (s1 >> 1) & 15, hB = s1 & 1;
  const size_t cs = (size_t)16 * 16 * 1024;     // 16 cb per chunk (f32 elems)
  constexpr int NCHUNK = 4;
  float acc[8];
#pragma unroll
  for (int i = 0; i < 8; i++) acc[i] = 0.f;
  for (int ch = 0; ch < NCHUNK; ch++) {
    __syncthreads();
    const uint4 iw = *(const uint4*)(i3b + (size_t)p * 64 + ch * 16);
    {
      const float* gA = lut + (size_t)ch * cs + ((size_t)cA * 16 + kA) * 1024 + o_base + hA * 8;
      const float* gB = lut + (size_t)ch * cs + ((size_t)cB * 16 + kB) * 1024 + o_base + hB * 8;
      float4 a0 = *(const float4*)gA;
      float4 a1 = *(const float4*)(gA + 4);
      float4 b0 = *(const float4*)gB;
      float4 b1 = *(const float4*)(gB + 4);
      half8v va, vb;
      va[0] = (half_t)a0.x; va[1] = (half_t)a0.y; va[2] = (half_t)a0.z; va[3] = (half_t)a0.w;
      va[4] = (half_t)a1.x; va[5] = (half_t)a1.y; va[6] = (half_t)a1.z; va[7] = (half_t)a1.w;
      vb[0] = (half_t)b0.x; vb[1] = (half_t)b0.y; vb[2] = (half_t)b0.z; vb[3] = (half_t)b0.w;
      vb[4] = (half_t)b1.x; vb[5] = (half_t)b1.y; vb[6] = (half_t)b1.z; vb[7] = (half_t)b1.w;
      *(half8v*)(s16 + cA * 640 + kA * 40 + hA * 8) = va;
      *(half8v*)(s16 + cB * 640 + kB * 40 + hB * 8) = vb;
    }
    __syncthreads();
#pragma unroll
    for (int grp = 0; grp < 2; grp++) {   // 8 cb per f32 flush
      uint32_t wa = grp ? iw.z : iw.x;
      uint32_t wb = grp ? iw.w : iw.y;
      half2v p0 = 0, p1 = 0, p2 = 0, p3 = 0;
#pragma unroll
      for (int j = 0; j < 8; j++) {
        uint32_t w = (j < 4) ? wa : wb;
        int idx = (int)((w >> ((j & 3) * 8)) & 15u);
        int cb_l = grp * 8 + j;
        const half8v v = *(const half8v*)(s16 + cb_l * 640 + idx * 40 + h * 8);
        const half2v* vp = (const half2v*)&v;
        p0 += vp[0]; p1 += vp[1]; p2 += vp[2]; p3 += vp[3];
      }
      acc[0] += (float)p0[0]; acc[1] += (float)p0[1];
      acc[2] += (float)p1[0]; acc[3] += (float)p1[1];
      acc[4] += (float)p2[0]; acc[5] += (float)p2[1];
      acc[6] += (float)p3[0]; acc[7] += (float)p3[1];
    }
  }
  const unsigned b = (unsigned)p / 196u;
  const unsigned pr = (unsigned)p - b * 196u;
  const int o = o_base + h * 8;
  const float* rp = res + ((size_t)b * 1024 + o) * PP + pr;
  float* op = out + ((size_t)b * 1024 + o) * PP + pr;
#pragma unroll
  for (int i = 0; i < 8; i++) {
    float v = acc[i] * scale[o + i] + bias[o + i] + rp[(size_t)i * PP];
    op[(size_t)i * PP] = fmaxf(v, 0.f);
  }
}

// ---------------------------------------------------------------------------

extern "C" void kernel_launch(void* const* d_in, const int* in_sizes, int n_in,
                              void* d_out, int out_size, void* d_ws, size_t ws_size,
                              hipStream_t stream) {
  const float* x   = (const float*)d_in[0];   // [32,1024,14,14]
  const float* c1c = (const float*)d_in[1];
  const float* c1l = (const float*)d_in[2];
  const float* c1s = (const float*)d_in[3];
  const float* c1b = (const float*)d_in[4];
  const float* c2c = (const float*)d_in[5];
  const float* c2l = (const float*)d_in[6];
  const float* c2s = (const float*)d_in[7];
  const float* c2b = (const float*)d_in[8];
  const float* c3c = (const float*)d_in[9];
  const float* c3l = (const float*)d_in[10];  // [64,16,1024]
  const float* c3s = (const float*)d_in[11];
  const float* c3b = (const float*)d_in[12];

  const size_t sz_i1  = (size_t)32 * BP * 4;      // 802,816 B
  const size_t sz_i2  = (size_t)32 * BP * 4;
  const size_t sz_i3b = (size_t)BP * 64;          // 401,408 B (byte indices)
  const size_t sz_o64 = (size_t)BP * 256 * 8;     // 12.85 MB

  char* w = (char*)d_ws;
  uint32_t* i1 = (uint32_t*)w; w += sz_i1;
  uint32_t* i2 = (uint32_t*)w; w += sz_i2;
  uint8_t* i3b = (uint8_t*)w;  w += sz_i3b;
  double* out1;
  if (ws_size >= (size_t)(w - (char*)d_ws) + sz_o64) {
    out1 = (double*)w;
  } else {
    // d_out (25.69 MB f32) holds one 12.85 MB f64 array in its first half;
    // accum3 (final) reads only i3b/x/c3l, then overwrites all of d_out.
    out1 = (double*)d_out;
  }

  const dim3 blkA(256), blkC(256);
  // layer 1: 1x1, 256 codebooks (dsub=4) over 1024 input channels
  assign_1x1<float><<<dim3(25, 32), blkA, 0, stream>>>(x, c1c, i1, 1024);
  accum_f64<256, 256, true, false, double><<<dim3(98, 16), blkC, 0, stream>>>(
      c1l, i1, c1s, c1b, nullptr, nullptr, out1);
  // layer 2: 3x3, 256 codebooks (dsub=9); epilogue fuses the layer-3 assign
  assign_3x3<<<dim3(25, 32), blkA, 0, stream>>>(out1, c2c, i2);
  accum_f64<256, 256, true, true, double><<<dim3(98, 16), blkC, 0, stream>>>(
      c2l, i2, c2s, c2b, c3c, i3b, nullptr);
  // layer 3: 64 codebooks over 256 channels; fused residual + relu
  accum3_f16<<<dim3(49, 64), blkC, 0, stream>>>(
      c3l, i3b, c3s, c3b, x, (float*)d_out);
}

// Round 5
// 242.142 us; speedup vs baseline: 1.7462x; 1.0400x over previous
//
#include <hip/hip_runtime.h>
#include <stdint.h>

#define PP 196            // 14*14
#define BP 6272           // 32*196

typedef _Float16 half_t;
typedef half_t half8v __attribute__((ext_vector_type(8)));
typedef half_t half2v __attribute__((ext_vector_type(2)));

// ---------------------------------------------------------------------------
// assign kernels (layers 1,2): nearest-centroid 4-bit indices, packed 8/u32.
// f32 SCREEN + f64 FIXUP (R7-proven): screen tracks best/second-best; iff any
// lane's gap < TAU the wave re-runs that codebook with the exact f64 formula.
// idx layout: idxp[cb/8][BP]
// ---------------------------------------------------------------------------

template <typename T>
__global__ __launch_bounds__(256) void assign_1x1(
    const T* __restrict__ in, const float* __restrict__ cents,
    uint32_t* __restrict__ idxp, int nchan) {
  __shared__ float  sf[8][16][4];     // screen rows (16 B, one b128)
  __shared__ double sd[8][16][6];     // [c2, c0..c3, pad]: 48 B rows
  const int chunk = blockIdx.y;
  const int t = threadIdx.x;
  for (int i = t; i < 512; i += 256) {
    float c = cents[(size_t)chunk * 512 + i];
    int cb = i >> 6, r = i & 63;      // r = k*4 + d
    sf[cb][r >> 2][r & 3] = c;
    sd[cb][r >> 2][1 + (r & 3)] = (double)c;
  }
  __syncthreads();
  if (t < 128) {
    int cb = t >> 4, k = t & 15;
    double s = 0.0;
#pragma unroll
    for (int d = 0; d < 4; d++) { double c = sd[cb][k][1 + d]; s += c * c; }
    sd[cb][k][0] = s;
  }
  __syncthreads();
  const int p = blockIdx.x * 256 + t;
  if (p >= BP) return;
  const unsigned b = (unsigned)p / 196u;
  const unsigned pr = (unsigned)p - b * 196u;
  const T* xb = in + ((size_t)b * nchan + chunk * 32) * PP + pr;
  T xr[32];
#pragma unroll
  for (int i = 0; i < 32; i++) xr[i] = xb[(size_t)i * PP];
  float xs2[32];
#pragma unroll
  for (int i = 0; i < 32; i++) xs2[i] = 2.f * (float)xr[i];
  uint32_t word = 0;
#pragma unroll 1
  for (int cb = 0; cb < 8; cb++) {
    float best = 1e30f, sec = 1e30f; int bi = 0;
#pragma unroll
    for (int k = 0; k < 16; k++) {
      const float4 c = *(const float4*)&sf[cb][k][0];
      float dist = c.x * (c.x - xs2[cb * 4 + 0]);
      dist = fmaf(c.y, c.y - xs2[cb * 4 + 1], dist);
      dist = fmaf(c.z, c.z - xs2[cb * 4 + 2], dist);
      dist = fmaf(c.w, c.w - xs2[cb * 4 + 3], dist);
      if (dist < best) { sec = best; best = dist; bi = k; }
      else sec = fminf(sec, dist);
    }
    if (__any(sec - best < 2e-4f)) {
      double xv[4];
#pragma unroll
      for (int d = 0; d < 4; d++) xv[d] = (double)xr[cb * 4 + d];
      double bb = 1e300; int bi64 = 0;
#pragma unroll
      for (int k = 0; k < 16; k++) {
        double dot = 0.0;
#pragma unroll
        for (int d = 0; d < 4; d++) dot = fma(xv[d], sd[cb][k][1 + d], dot);
        double dist = sd[cb][k][0] - 2.0 * dot;
        if (dist < bb) { bb = dist; bi64 = k; }   // strict <: first-min
      }
      bi = bi64;
    }
    word |= (uint32_t)bi << (4 * cb);
  }
  idxp[(size_t)chunk * BP + p] = word;
}

__global__ __launch_bounds__(256) void assign_3x3(
    const double* __restrict__ in, const float* __restrict__ cents,
    uint32_t* __restrict__ idxp) {
  __shared__ float  sf[8][16][12];    // [c2f, c0..c8, pad, pad]: 48 B rows
  __shared__ double sd[8][16][10];    // [c2, c0..c8]: 80 B rows
  const int chunk = blockIdx.y;
  const int c0g = chunk * 8;
  const int t = threadIdx.x;
  for (int i = t; i < 1152; i += 256) {
    int cb = i / 144, r = i - cb * 144;
    int k = r / 9, d = r - k * 9;
    float c = cents[(size_t)(c0g + cb) * 144 + k * 9 + d];
    sf[cb][k][1 + d] = c;
    sd[cb][k][1 + d] = (double)c;
  }
  __syncthreads();
  if (t < 128) {
    int cb = t >> 4, k = t & 15;
    double s = 0.0;
    float s32 = 0.f;
#pragma unroll
    for (int d = 0; d < 9; d++) {
      double c = sd[cb][k][1 + d]; s += c * c;
      float cf = sf[cb][k][1 + d]; s32 += cf * cf;
    }
    sd[cb][k][0] = s;
    sf[cb][k][0] = s32;
  }
  __syncthreads();
  const int p = blockIdx.x * 256 + t;
  if (p >= BP) return;
  const unsigned b = (unsigned)p / 196u;
  const unsigned pr = (unsigned)p - b * 196u;
  const int oh = pr / 14, ow = pr - oh * 14;
  uint32_t word = 0;
#pragma unroll 1
  for (int cb = 0; cb < 8; cb++) {
    const double* base = in + ((size_t)b * 256 + (c0g + cb)) * PP;
    double v64[9]; float v32[9];
#pragma unroll
    for (int r = 0; r < 3; r++) {
#pragma unroll
      for (int cc = 0; cc < 3; cc++) {
        int hh = oh + r - 1, ww = ow + cc - 1;
        bool ok = (hh >= 0) & (hh < 14) & (ww >= 0) & (ww < 14);
        double v = ok ? base[hh * 14 + ww] : 0.0;
        v64[r * 3 + cc] = v;
        v32[r * 3 + cc] = (float)v;
      }
    }
    float best = 1e30f, sec = 1e30f; int bi = 0;
#pragma unroll
    for (int k = 0; k < 16; k++) {
      const float4 cA = *(const float4*)&sf[cb][k][0];  // c2f,c0,c1,c2
      const float4 cB = *(const float4*)&sf[cb][k][4];  // c3..c6
      const float4 cC = *(const float4*)&sf[cb][k][8];  // c7,c8,pad,pad
      float dot = v32[0] * cA.y;
      dot = fmaf(v32[1], cA.z, dot);
      dot = fmaf(v32[2], cA.w, dot);
      dot = fmaf(v32[3], cB.x, dot);
      dot = fmaf(v32[4], cB.y, dot);
      dot = fmaf(v32[5], cB.z, dot);
      dot = fmaf(v32[6], cB.w, dot);
      dot = fmaf(v32[7], cC.x, dot);
      dot = fmaf(v32[8], cC.y, dot);
      float dist = fmaf(-2.f, dot, cA.x);
      if (dist < best) { sec = best; best = dist; bi = k; }
      else sec = fminf(sec, dist);
    }
    if (__any(sec - best < 4e-4f)) {
      double bb = 1e300; int bi64 = 0;
#pragma unroll
      for (int k = 0; k < 16; k++) {
        double dot = 0.0;
#pragma unroll
        for (int d = 0; d < 9; d++) dot = fma(v64[d], sd[cb][k][1 + d], dot);
        double dist = sd[cb][k][0] - 2.0 * dot;
        if (dist < bb) { bb = dist; bi64 = k; }
      }
      bi = bi64;
    }
    word |= (uint32_t)bi << (4 * cb);
  }
  idxp[(size_t)chunk * BP + p] = word;
}

// ---------------------------------------------------------------------------
// accum v7 (f64-grade): coalesced staging + QUAD-SWIZZLED conflict-free LDS.
// Constraint set isolated over R0-R4:
//  (1) global coalescing: consecutive lanes must read consecutive 16B of one
//      LUT row (R3 violated -> 64 req/wave-load, 65us TA-bound).
//  (2) write conflicts: LDS services ds_write_b128 in groups of 8 lanes
//      (8x16B = one 128B bank sweep); the group's 8 slots must hit 8
//      DISTINCT bank-quads. R4's sigma gave only 2 quads (4-way) -> 9.66M
//      conflicts ~ 15.7us. R3's lane-linear gave 8 distinct -> ~0.
//  (3) gather conflicts: per wave (q fixed), idx in 0..15 must map 2-to-1
//      onto 8 quads with the 2 addrs distinct -> 2-way = free.
// v7 satisfies all three with a bijective in-block swizzle:
//   slot(cb,q_s,k) = cb*64 + q_s*16 + (k&8) + ((k + 2*q_s)&7)
//   - write group (q_s=lane&3, k in {2m,2m+1}): quads (k+2q_s)&7 = 8 distinct
//   - gather (q fixed): quad = (idx+2q)&7, 2-to-1, pair differs in k&8 bit
//   - source = R0/R4's coalesced pattern (4 lanes = 64B contiguous)
// PAIRWISE accumulation: adjacent cb pairs summed in f32 (err ~7e-7 rms),
// then one cvt+f64 add per pair -- identical arithmetic order to v2.
// FUSE3 (layer 2): epilogue computes the layer-3 assignment in-register.
// ---------------------------------------------------------------------------
template <int NCB, int NOUT, bool RELU, bool FUSE3, typename OutT>
__global__ __launch_bounds__(256) void accum_f64(
    const float* __restrict__ lut, const uint32_t* __restrict__ idxp,
    const float* __restrict__ scale, const float* __restrict__ bias,
    const float* __restrict__ c3cent, uint8_t* __restrict__ i3b,
    OutT* __restrict__ out) {
  __shared__ float s_lut[4096];       // 16 KB: 16 cb x 16 k x 16 out
  __shared__ float  c3f[4][16][4];
  __shared__ float  c3c2f[4][16];
  __shared__ double c3d[4][16][4];
  __shared__ double c3c2d[4][16];
  const int t = threadIdx.x;
  const int lane = t & 63;
  const int q = t >> 6;                 // channel quad 0..3 (wave id)
  const int p = blockIdx.x * 64 + lane; // 98*64 = 6272 = BP exactly
  const int o_base = blockIdx.y * 16;
  if (FUSE3 && t < 64) {
    int cb_l = t >> 4, k = t & 15;
    const float4 cf = *(const float4*)(c3cent + ((size_t)(blockIdx.y * 4 + cb_l)) * 64 + k * 4);
    c3f[cb_l][k][0] = cf.x; c3f[cb_l][k][1] = cf.y;
    c3f[cb_l][k][2] = cf.z; c3f[cb_l][k][3] = cf.w;
    double d0 = (double)cf.x, d1 = (double)cf.y, d2 = (double)cf.z, d3 = (double)cf.w;
    c3d[cb_l][k][0] = d0; c3d[cb_l][k][1] = d1;
    c3d[cb_l][k][2] = d2; c3d[cb_l][k][3] = d3;
    double s = 0.0; s += d0 * d0; s += d1 * d1; s += d2 * d2; s += d3 * d3;
    c3c2d[cb_l][k] = s;
    float s32 = 0.f; s32 += cf.x * cf.x; s32 += cf.y * cf.y;
    s32 += cf.z * cf.z; s32 += cf.w * cf.w;
    c3c2f[cb_l][k] = s32;
  }
  // staging ownership (coalesced source, R4): thread t owns cb=(t>>6)+4j,
  // q_s = t&3, k = (t>>2)&15; source row (ch*256 + cb*16 + k), col
  // o_base + q_s*4 -> 4 consecutive lanes = 64 contiguous bytes of one row.
  const float* src = lut + ((size_t)(t >> 6) * 16 + ((t >> 2) & 15)) * NOUT
                         + o_base + (t & 3) * 4;
  const int kk = (t >> 2) & 15, qs = t & 3;
  const int sslot = (t >> 6) * 64 + qs * 16 + ((kk & 8) | ((kk + 2 * qs) & 7));
  const int q2 = q * 2;               // wave-uniform gather swizzle term
  double a0 = 0, a1 = 0, a2 = 0, a3 = 0;
  constexpr int NCHUNK = NCB / 16;
  for (int ch = 0; ch < NCHUNK; ch++) {
    __syncthreads();               // prior chunk's gathers done before overwrite
    uint32_t w0 = idxp[(size_t)(ch * 2) * BP + p];
    uint32_t w1 = idxp[(size_t)(ch * 2 + 1) * BP + p];
    {
      const float* g = src + (size_t)(ch * 256) * NOUT;
#pragma unroll
      for (int j = 0; j < 4; j++) {
        float4 v = *(const float4*)(g + (size_t)(64 * j) * NOUT);
        *(float4*)(s_lut + (sslot + 256 * j) * 4) = v;
      }
    }
    __syncthreads();               // chunk published
    const float* buf = s_lut + q * 64;
#pragma unroll
    for (int j = 0; j < 8; j++) {  // cb pair (2j, 2j+1)
      uint32_t w = (j < 4) ? w0 : w1;
      int sh = (j & 3) * 8;
      int i0 = (int)((w >> sh) & 15u);
      int i1 = (int)((w >> (sh + 4)) & 15u);
      int o0 = (i0 & 8) | ((i0 + q2) & 7);   // swizzled slot within (cb, q)
      int o1 = (i1 & 8) | ((i1 + q2) & 7);
      const float4 va = *(const float4*)(buf + (2 * j) * 256 + o0 * 4);
      const float4 vb = *(const float4*)(buf + (2 * j + 1) * 256 + o1 * 4);
      float s0 = va.x + vb.x, s1 = va.y + vb.y;
      float s2 = va.z + vb.z, s3 = va.w + vb.w;
      a0 += (double)s0; a1 += (double)s1; a2 += (double)s2; a3 += (double)s3;
    }
  }
  const unsigned b = (unsigned)p / 196u;
  const unsigned pr = (unsigned)p - b * 196u;
  const int o = o_base + q * 4;
  const float4 sc = *(const float4*)(scale + o);
  const float4 bs = *(const float4*)(bias + o);
  double r0 = a0 * (double)sc.x + (double)bs.x;
  double r1 = a1 * (double)sc.y + (double)bs.y;
  double r2 = a2 * (double)sc.z + (double)bs.z;
  double r3 = a3 * (double)sc.w + (double)bs.w;
  if (RELU) {
    r0 = fmax(r0, 0.0); r1 = fmax(r1, 0.0);
    r2 = fmax(r2, 0.0); r3 = fmax(r3, 0.0);
  }
  if (FUSE3) {
    // layer-3 assignment for codebook cb3 = blockIdx.y*4 + q (this thread's 4 ch)
    const int cb_l = q;
    float x0 = (float)r0, x1 = (float)r1, x2 = (float)r2, x3 = (float)r3;
    float best = 1e30f, sec = 1e30f; int bi = 0;
#pragma unroll
    for (int k = 0; k < 16; k++) {
      const float4 c = *(const float4*)&c3f[cb_l][k][0];
      float dot = x0 * c.x;
      dot = fmaf(x1, c.y, dot);
      dot = fmaf(x2, c.z, dot);
      dot = fmaf(x3, c.w, dot);
      float dist = fmaf(-2.f, dot, c3c2f[cb_l][k]);
      if (dist < best) { sec = best; best = dist; bi = k; }
      else sec = fminf(sec, dist);
    }
    if (__any(sec - best < 1e-3f)) {
      double bb = 1e300; int bi64 = 0;
#pragma unroll
      for (int k = 0; k < 16; k++) {
        double dot = 0.0;
        dot = fma(r0, c3d[cb_l][k][0], dot);
        dot = fma(r1, c3d[cb_l][k][1], dot);
        dot = fma(r2, c3d[cb_l][k][2], dot);
        dot = fma(r3, c3d[cb_l][k][3], dot);
        double dist = c3c2d[cb_l][k] - 2.0 * dot;
        if (dist < bb) { bb = dist; bi64 = k; }   // strict <: first-min
      }
      bi = bi64;
    }
    i3b[(size_t)p * 64 + blockIdx.y * 4 + q] = (uint8_t)bi;
  } else {
    OutT* op = out + ((size_t)b * NOUT + o) * PP + pr;
    op[0 * PP] = (OutT)r0; op[1 * PP] = (OutT)r1;
    op[2 * PP] = (OutT)r2; op[3 * PP] = (OutT)r3;
  }
}

// ---------------------------------------------------------------------------
// accum3: final layer (no downstream argmin). f32 LUT -> f16 staged in-register;
// packed v_pk_add_f16 inner loop, partials flushed to f32 every 8 codebooks.
// Index read: one dwordx4 of bytes per chunk from i3b[p][cb]. Rows 40 halfs
// (80 B): bank-quad (5*idx+h)%8 bijective -> 2-way = free.
// grid (49, 64), block 256 (4 waves): 128 positions x 16 channels.
// ---------------------------------------------------------------------------
__global__ __launch_bounds__(256) void accum3_f16(
    const float* __restrict__ lut, const uint8_t* __restrict__ i3b,
    const float* __restrict__ scale, const float* __restrict__ bias,
    const float* __restrict__ res, float* __restrict__ out) {
  __shared__ half_t s16[16 * 640];   // 20 KB
  const int t = threadIdx.x;
  const int lane = t & 63;
  const int wave = t >> 6;           // 0..3
  const int h = wave & 1;            // channel half (8 f16 ch)
  const int pg = wave >> 1;          // 0..1
  const int p = blockIdx.x * 128 + pg * 64 + lane;
  const int o_base = blockIdx.y * 16;
  // staging slots s0=t, s1=t+256 of 512: (cb=s>>5, k=(s>>1)&15, hh=s&1)
  const int s0 = t, s1 = t + 256;
  const int cA = s0 >> 5, kA = (s0 >> 1) & 15, hA = s0 & 1;
  const int cB = s1 >> 5, kB = (s1 >> 1) & 15, hB = s1 & 1;
  const size_t cs = (size_t)16 * 16 * 1024;     // 16 cb per chunk (f32 elems)
  constexpr int NCHUNK = 4;
  float acc[8];
#pragma unroll
  for (int i = 0; i < 8; i++) acc[i] = 0.f;
  for (int ch = 0; ch < NCHUNK; ch++) {
    __syncthreads();
    const uint4 iw = *(const uint4*)(i3b + (size_t)p * 64 + ch * 16);
    {
      const float* gA = lut + (size_t)ch * cs + ((size_t)cA * 16 + kA) * 1024 + o_base + hA * 8;
      const float* gB = lut + (size_t)ch * cs + ((size_t)cB * 16 + kB) * 1024 + o_base + hB * 8;
      float4 a0 = *(const float4*)gA;
      float4 a1 = *(const float4*)(gA + 4);
      float4 b0 = *(const float4*)gB;
      float4 b1 = *(const float4*)(gB + 4);
      half8v va, vb;
      va[0] = (half_t)a0.x; va[1] = (half_t)a0.y; va[2] = (half_t)a0.z; va[3] = (half_t)a0.w;
      va[4] = (half_t)a1.x; va[5] = (half_t)a1.y; va[6] = (half_t)a1.z; va[7] = (half_t)a1.w;
      vb[0] = (half_t)b0.x; vb[1] = (half_t)b0.y; vb[2] = (half_t)b0.z; vb[3] = (half_t)b0.w;
      vb[4] = (half_t)b1.x; vb[5] = (half_t)b1.y; vb[6] = (half_t)b1.z; vb[7] = (half_t)b1.w;
      *(half8v*)(s16 + cA * 640 + kA * 40 + hA * 8) = va;
      *(half8v*)(s16 + cB * 640 + kB * 40 + hB * 8) = vb;
    }
    __syncthreads();
#pragma unroll
    for (int grp = 0; grp < 2; grp++) {   // 8 cb per f32 flush
      uint32_t wa = grp ? iw.z : iw.x;
      uint32_t wb = grp ? iw.w : iw.y;
      half2v p0 = 0, p1 = 0, p2 = 0, p3 = 0;
#pragma unroll
      for (int j = 0; j < 8; j++) {
        uint32_t w = (j < 4) ? wa : wb;
        int idx = (int)((w >> ((j & 3) * 8)) & 15u);
        int cb_l = grp * 8 + j;
        const half8v v = *(const half8v*)(s16 + cb_l * 640 + idx * 40 + h * 8);
        const half2v* vp = (const half2v*)&v;
        p0 += vp[0]; p1 += vp[1]; p2 += vp[2]; p3 += vp[3];
      }
      acc[0] += (float)p0[0]; acc[1] += (float)p0[1];
      acc[2] += (float)p1[0]; acc[3] += (float)p1[1];
      acc[4] += (float)p2[0]; acc[5] += (float)p2[1];
      acc[6] += (float)p3[0]; acc[7] += (float)p3[1];
    }
  }
  const unsigned b = (unsigned)p / 196u;
  const unsigned pr = (unsigned)p - b * 196u;
  const int o = o_base + h * 8;
  const float* rp = res + ((size_t)b * 1024 + o) * PP + pr;
  float* op = out + ((size_t)b * 1024 + o) * PP + pr;
#pragma unroll
  for (int i = 0; i < 8; i++) {
    float v = acc[i] * scale[o + i] + bias[o + i] + rp[(size_t)i * PP];
    op[(size_t)i * PP] = fmaxf(v, 0.f);
  }
}

// ---------------------------------------------------------------------------

extern "C" void kernel_launch(void* const* d_in, const int* in_sizes, int n_in,
                              void* d_out, int out_size, void* d_ws, size_t ws_size,
                              hipStream_t stream) {
  const float* x   = (const float*)d_in[0];   // [32,1024,14,14]
  const float* c1c = (const float*)d_in[1];
  const float* c1l = (const float*)d_in[2];
  const float* c1s = (const float*)d_in[3];
  const float* c1b = (const float*)d_in[4];
  const float* c2c = (const float*)d_in[5];
  const float* c2l = (const float*)d_in[6];
  const float* c2s = (const float*)d_in[7];
  const float* c2b = (const float*)d_in[8];
  const float* c3c = (const float*)d_in[9];
  const float* c3l = (const float*)d_in[10];  // [64,16,1024]
  const float* c3s = (const float*)d_in[11];
  const float* c3b = (const float*)d_in[12];

  const size_t sz_i1  = (size_t)32 * BP * 4;      // 802,816 B
  const size_t sz_i2  = (size_t)32 * BP * 4;
  const size_t sz_i3b = (size_t)BP * 64;          // 401,408 B (byte indices)
  const size_t sz_o64 = (size_t)BP * 256 * 8;     // 12.85 MB

  char* w = (char*)d_ws;
  uint32_t* i1 = (uint32_t*)w; w += sz_i1;
  uint32_t* i2 = (uint32_t*)w; w += sz_i2;
  uint8_t* i3b = (uint8_t*)w;  w += sz_i3b;
  double* out1;
  if (ws_size >= (size_t)(w - (char*)d_ws) + sz_o64) {
    out1 = (double*)w;
  } else {
    // d_out (25.69 MB f32) holds one 12.85 MB f64 array in its first half;
    // accum3 (final) reads only i3b/x/c3l, then overwrites all of d_out.
    out1 = (double*)d_out;
  }

  const dim3 blkA(256), blkC(256);
  // layer 1: 1x1, 256 codebooks (dsub=4) over 1024 input channels
  assign_1x1<float><<<dim3(25, 32), blkA, 0, stream>>>(x, c1c, i1, 1024);
  accum_f64<256, 256, true, false, double><<<dim3(98, 16), blkC, 0, stream>>>(
      c1l, i1, c1s, c1b, nullptr, nullptr, out1);
  // layer 2: 3x3, 256 codebooks (dsub=9); epilogue fuses the layer-3 assign
  assign_3x3<<<dim3(25, 32), blkA, 0, stream>>>(out1, c2c, i2);
  accum_f64<256, 256, true, true, double><<<dim3(98, 16), blkC, 0, stream>>>(
      c2l, i2, c2s, c2b, c3c, i3b, nullptr);
  // layer 3: 64 codebooks over 256 channels; fused residual + relu
  accum3_f16<<<dim3(49, 64), blkC, 0, stream>>>(
      c3l, i3b, c3s, c3b, x, (float*)d_out);
}

// Round 6
// 226.651 us; speedup vs baseline: 1.8656x; 1.0683x over previous
//
#include <hip/hip_runtime.h>
#include <stdint.h>

#define PP 196            // 14*14
#define BP 6272           // 32*196

typedef _Float16 half_t;
typedef half_t half8v __attribute__((ext_vector_type(8)));
typedef half_t half4v __attribute__((ext_vector_type(4)));
typedef half_t half2v __attribute__((ext_vector_type(2)));

// ---------------------------------------------------------------------------
// assign kernels (layers 1,2): nearest-centroid 4-bit indices, packed 8/u32.
// f32 SCREEN + f64 FIXUP (R7-proven): screen tracks best/second-best; iff any
// lane's gap < TAU the wave re-runs that codebook with the exact f64 formula.
// idx layout: idxp[cb/8][BP]
// ---------------------------------------------------------------------------

template <typename T>
__global__ __launch_bounds__(256) void assign_1x1(
    const T* __restrict__ in, const float* __restrict__ cents,
    uint32_t* __restrict__ idxp, int nchan) {
  __shared__ float  sf[8][16][4];     // screen rows (16 B, one b128)
  __shared__ double sd[8][16][6];     // [c2, c0..c3, pad]: 48 B rows
  const int chunk = blockIdx.y;
  const int t = threadIdx.x;
  for (int i = t; i < 512; i += 256) {
    float c = cents[(size_t)chunk * 512 + i];
    int cb = i >> 6, r = i & 63;      // r = k*4 + d
    sf[cb][r >> 2][r & 3] = c;
    sd[cb][r >> 2][1 + (r & 3)] = (double)c;
  }
  __syncthreads();
  if (t < 128) {
    int cb = t >> 4, k = t & 15;
    double s = 0.0;
#pragma unroll
    for (int d = 0; d < 4; d++) { double c = sd[cb][k][1 + d]; s += c * c; }
    sd[cb][k][0] = s;
  }
  __syncthreads();
  const int p = blockIdx.x * 256 + t;
  if (p >= BP) return;
  const unsigned b = (unsigned)p / 196u;
  const unsigned pr = (unsigned)p - b * 196u;
  const T* xb = in + ((size_t)b * nchan + chunk * 32) * PP + pr;
  T xr[32];
#pragma unroll
  for (int i = 0; i < 32; i++) xr[i] = xb[(size_t)i * PP];
  float xs2[32];
#pragma unroll
  for (int i = 0; i < 32; i++) xs2[i] = 2.f * (float)xr[i];
  uint32_t word = 0;
#pragma unroll 1
  for (int cb = 0; cb < 8; cb++) {
    float best = 1e30f, sec = 1e30f; int bi = 0;
#pragma unroll
    for (int k = 0; k < 16; k++) {
      const float4 c = *(const float4*)&sf[cb][k][0];
      float dist = c.x * (c.x - xs2[cb * 4 + 0]);
      dist = fmaf(c.y, c.y - xs2[cb * 4 + 1], dist);
      dist = fmaf(c.z, c.z - xs2[cb * 4 + 2], dist);
      dist = fmaf(c.w, c.w - xs2[cb * 4 + 3], dist);
      if (dist < best) { sec = best; best = dist; bi = k; }
      else sec = fminf(sec, dist);
    }
    if (__any(sec - best < 2e-4f)) {
      double xv[4];
#pragma unroll
      for (int d = 0; d < 4; d++) xv[d] = (double)xr[cb * 4 + d];
      double bb = 1e300; int bi64 = 0;
#pragma unroll
      for (int k = 0; k < 16; k++) {
        double dot = 0.0;
#pragma unroll
        for (int d = 0; d < 4; d++) dot = fma(xv[d], sd[cb][k][1 + d], dot);
        double dist = sd[cb][k][0] - 2.0 * dot;
        if (dist < bb) { bb = dist; bi64 = k; }   // strict <: first-min
      }
      bi = bi64;
    }
    word |= (uint32_t)bi << (4 * cb);
  }
  idxp[(size_t)chunk * BP + p] = word;
}

__global__ __launch_bounds__(256) void assign_3x3(
    const double* __restrict__ in, const float* __restrict__ cents,
    uint32_t* __restrict__ idxp) {
  __shared__ float  sf[8][16][12];    // [c2f, c0..c8, pad, pad]: 48 B rows
  __shared__ double sd[8][16][10];    // [c2, c0..c8]: 80 B rows
  const int chunk = blockIdx.y;
  const int c0g = chunk * 8;
  const int t = threadIdx.x;
  for (int i = t; i < 1152; i += 256) {
    int cb = i / 144, r = i - cb * 144;
    int k = r / 9, d = r - k * 9;
    float c = cents[(size_t)(c0g + cb) * 144 + k * 9 + d];
    sf[cb][k][1 + d] = c;
    sd[cb][k][1 + d] = (double)c;
  }
  __syncthreads();
  if (t < 128) {
    int cb = t >> 4, k = t & 15;
    double s = 0.0;
    float s32 = 0.f;
#pragma unroll
    for (int d = 0; d < 9; d++) {
      double c = sd[cb][k][1 + d]; s += c * c;
      float cf = sf[cb][k][1 + d]; s32 += cf * cf;
    }
    sd[cb][k][0] = s;
    sf[cb][k][0] = s32;
  }
  __syncthreads();
  const int p = blockIdx.x * 256 + t;
  if (p >= BP) return;
  const unsigned b = (unsigned)p / 196u;
  const unsigned pr = (unsigned)p - b * 196u;
  const int oh = pr / 14, ow = pr - oh * 14;
  uint32_t word = 0;
#pragma unroll 1
  for (int cb = 0; cb < 8; cb++) {
    const double* base = in + ((size_t)b * 256 + (c0g + cb)) * PP;
    double v64[9]; float v32[9];
#pragma unroll
    for (int r = 0; r < 3; r++) {
#pragma unroll
      for (int cc = 0; cc < 3; cc++) {
        int hh = oh + r - 1, ww = ow + cc - 1;
        bool ok = (hh >= 0) & (hh < 14) & (ww >= 0) & (ww < 14);
        double v = ok ? base[hh * 14 + ww] : 0.0;
        v64[r * 3 + cc] = v;
        v32[r * 3 + cc] = (float)v;
      }
    }
    float best = 1e30f, sec = 1e30f; int bi = 0;
#pragma unroll
    for (int k = 0; k < 16; k++) {
      const float4 cA = *(const float4*)&sf[cb][k][0];  // c2f,c0,c1,c2
      const float4 cB = *(const float4*)&sf[cb][k][4];  // c3..c6
      const float4 cC = *(const float4*)&sf[cb][k][8];  // c7,c8,pad,pad
      float dot = v32[0] * cA.y;
      dot = fmaf(v32[1], cA.z, dot);
      dot = fmaf(v32[2], cA.w, dot);
      dot = fmaf(v32[3], cB.x, dot);
      dot = fmaf(v32[4], cB.y, dot);
      dot = fmaf(v32[5], cB.z, dot);
      dot = fmaf(v32[6], cB.w, dot);
      dot = fmaf(v32[7], cC.x, dot);
      dot = fmaf(v32[8], cC.y, dot);
      float dist = fmaf(-2.f, dot, cA.x);
      if (dist < best) { sec = best; best = dist; bi = k; }
      else sec = fminf(sec, dist);
    }
    if (__any(sec - best < 4e-4f)) {
      double bb = 1e300; int bi64 = 0;
#pragma unroll
      for (int k = 0; k < 16; k++) {
        double dot = 0.0;
#pragma unroll
        for (int d = 0; d < 9; d++) dot = fma(v64[d], sd[cb][k][1 + d], dot);
        double dist = sd[cb][k][0] - 2.0 * dot;
        if (dist < bb) { bb = dist; bi64 = k; }
      }
      bi = bi64;
    }
    word |= (uint32_t)bi << (4 * cb);
  }
  idxp[(size_t)chunk * BP + p] = word;
}

// ---------------------------------------------------------------------------
// accum v8 (f64-grade): R5's proven structure with VALU trims. R5 counters:
// conflicts 25K (solved), VALUBusy 56%, dur 53.4us vs LDS-issue floor ~39us.
// v8 attacks VALU:
//  - XOR swizzle (1 op vs 4): slot(cb,qs,k) = cb*64 + qs*16 + (k ^ 2qs).
//    write group (8 lanes: qs=0..3, k in {2m,2m+1}): quads (k^2qs)&7 = 8
//    distinct -> conflict-free. gather (wave q): o = idx ^ 2q, 2-to-1 onto
//    quads, pair differs in bit3 -> 2-way = free. Coalesced source (R4).
//  - QUAD-f32 accumulation: 4 cb summed in f32 (3 adds), ONE cvt+f64 add
//    per quad: cvt 32->16, f64-add 32->16 per chunk (f64 add = 4cy).
//    Extra f32 err ~3e-7 rms, negligible vs tolerance.
// FUSE3 (layer 2): epilogue computes the layer-3 assignment in-register;
// i3b layout TRANSPOSED to [chunk16][p][16B] so accum3's index read is
// lane-contiguous (was 64 req/wave-load at p*64 stride).
// ---------------------------------------------------------------------------
template <int NCB, int NOUT, bool RELU, bool FUSE3, typename OutT>
__global__ __launch_bounds__(256) void accum_f64(
    const float* __restrict__ lut, const uint32_t* __restrict__ idxp,
    const float* __restrict__ scale, const float* __restrict__ bias,
    const float* __restrict__ c3cent, uint8_t* __restrict__ i3b,
    OutT* __restrict__ out) {
  __shared__ float s_lut[4096];       // 16 KB: 16 cb x 16 k x 16 out
  __shared__ float  c3f[4][16][4];
  __shared__ float  c3c2f[4][16];
  __shared__ double c3d[4][16][4];
  __shared__ double c3c2d[4][16];
  const int t = threadIdx.x;
  const int lane = t & 63;
  const int q = t >> 6;                 // channel quad 0..3 (wave id)
  const int p = blockIdx.x * 64 + lane; // 98*64 = 6272 = BP exactly
  const int o_base = blockIdx.y * 16;
  if (FUSE3 && t < 64) {
    int cb_l = t >> 4, k = t & 15;
    const float4 cf = *(const float4*)(c3cent + ((size_t)(blockIdx.y * 4 + cb_l)) * 64 + k * 4);
    c3f[cb_l][k][0] = cf.x; c3f[cb_l][k][1] = cf.y;
    c3f[cb_l][k][2] = cf.z; c3f[cb_l][k][3] = cf.w;
    double d0 = (double)cf.x, d1 = (double)cf.y, d2 = (double)cf.z, d3 = (double)cf.w;
    c3d[cb_l][k][0] = d0; c3d[cb_l][k][1] = d1;
    c3d[cb_l][k][2] = d2; c3d[cb_l][k][3] = d3;
    double s = 0.0; s += d0 * d0; s += d1 * d1; s += d2 * d2; s += d3 * d3;
    c3c2d[cb_l][k] = s;
    float s32 = 0.f; s32 += cf.x * cf.x; s32 += cf.y * cf.y;
    s32 += cf.z * cf.z; s32 += cf.w * cf.w;
    c3c2f[cb_l][k] = s32;
  }
  // staging ownership (coalesced source, R4): thread t owns cb=(t>>6)+4j,
  // q_s = t&3, k = (t>>2)&15; source row (ch*256 + cb*16 + k), col
  // o_base + q_s*4 -> 4 consecutive lanes = 64 contiguous bytes of one row.
  const float* src = lut + ((size_t)(t >> 6) * 16 + ((t >> 2) & 15)) * NOUT
                         + o_base + (t & 3) * 4;
  const int kk = (t >> 2) & 15, qs = t & 3;
  const int sslot = (t >> 6) * 64 + qs * 16 + (kk ^ (2 * qs));
  const int q2 = q * 2;               // wave-uniform gather swizzle term
  double a0 = 0, a1 = 0, a2 = 0, a3 = 0;
  constexpr int NCHUNK = NCB / 16;
  for (int ch = 0; ch < NCHUNK; ch++) {
    __syncthreads();               // prior chunk's gathers done before overwrite
    uint32_t w0 = idxp[(size_t)(ch * 2) * BP + p];
    uint32_t w1 = idxp[(size_t)(ch * 2 + 1) * BP + p];
    {
      const float* g = src + (size_t)(ch * 256) * NOUT;
#pragma unroll
      for (int j = 0; j < 4; j++) {
        float4 v = *(const float4*)(g + (size_t)(64 * j) * NOUT);
        *(float4*)(s_lut + (sslot + 256 * j) * 4) = v;
      }
    }
    __syncthreads();               // chunk published
    const float* buf = s_lut + q * 64;
#pragma unroll
    for (int jq = 0; jq < 4; jq++) {   // cb quad (4jq .. 4jq+3)
      uint32_t w = (jq < 2) ? w0 : w1;
      int sh = (jq & 1) * 16;
      int i0 = (int)((w >> sh) & 15u);
      int i1 = (int)((w >> (sh + 4)) & 15u);
      int i2 = (int)((w >> (sh + 8)) & 15u);
      int i3 = (int)((w >> (sh + 12)) & 15u);
      const float4 va = *(const float4*)(buf + (4 * jq)     * 256 + (i0 ^ q2) * 4);
      const float4 vb = *(const float4*)(buf + (4 * jq + 1) * 256 + (i1 ^ q2) * 4);
      const float4 vc = *(const float4*)(buf + (4 * jq + 2) * 256 + (i2 ^ q2) * 4);
      const float4 vd = *(const float4*)(buf + (4 * jq + 3) * 256 + (i3 ^ q2) * 4);
      float s0 = (va.x + vb.x) + (vc.x + vd.x);
      float s1 = (va.y + vb.y) + (vc.y + vd.y);
      float s2 = (va.z + vb.z) + (vc.z + vd.z);
      float s3 = (va.w + vb.w) + (vc.w + vd.w);
      a0 += (double)s0; a1 += (double)s1; a2 += (double)s2; a3 += (double)s3;
    }
  }
  const unsigned b = (unsigned)p / 196u;
  const unsigned pr = (unsigned)p - b * 196u;
  const int o = o_base + q * 4;
  const float4 sc = *(const float4*)(scale + o);
  const float4 bs = *(const float4*)(bias + o);
  double r0 = a0 * (double)sc.x + (double)bs.x;
  double r1 = a1 * (double)sc.y + (double)bs.y;
  double r2 = a2 * (double)sc.z + (double)bs.z;
  double r3 = a3 * (double)sc.w + (double)bs.w;
  if (RELU) {
    r0 = fmax(r0, 0.0); r1 = fmax(r1, 0.0);
    r2 = fmax(r2, 0.0); r3 = fmax(r3, 0.0);
  }
  if (FUSE3) {
    // layer-3 assignment for codebook cb3 = blockIdx.y*4 + q (this thread's 4 ch)
    const int cb_l = q;
    float x0 = (float)r0, x1 = (float)r1, x2 = (float)r2, x3 = (float)r3;
    float best = 1e30f, sec = 1e30f; int bi = 0;
#pragma unroll
    for (int k = 0; k < 16; k++) {
      const float4 c = *(const float4*)&c3f[cb_l][k][0];
      float dot = x0 * c.x;
      dot = fmaf(x1, c.y, dot);
      dot = fmaf(x2, c.z, dot);
      dot = fmaf(x3, c.w, dot);
      float dist = fmaf(-2.f, dot, c3c2f[cb_l][k]);
      if (dist < best) { sec = best; best = dist; bi = k; }
      else sec = fminf(sec, dist);
    }
    if (__any(sec - best < 1e-3f)) {
      double bb = 1e300; int bi64 = 0;
#pragma unroll
      for (int k = 0; k < 16; k++) {
        double dot = 0.0;
        dot = fma(r0, c3d[cb_l][k][0], dot);
        dot = fma(r1, c3d[cb_l][k][1], dot);
        dot = fma(r2, c3d[cb_l][k][2], dot);
        dot = fma(r3, c3d[cb_l][k][3], dot);
        double dist = c3c2d[cb_l][k] - 2.0 * dot;
        if (dist < bb) { bb = dist; bi64 = k; }   // strict <: first-min
      }
      bi = bi64;
    }
    // transposed layout: i3b[chunk16][p][16]  (chunk16 = cb3>>4, byte = cb3&15)
    i3b[((size_t)(blockIdx.y >> 2) * BP + p) * 16 + (blockIdx.y & 3) * 4 + q] =
        (uint8_t)bi;
  } else {
    OutT* op = out + ((size_t)b * NOUT + o) * PP + pr;
    op[0 * PP] = (OutT)r0; op[1 * PP] = (OutT)r1;
    op[2 * PP] = (OutT)r2; op[3 * PP] = (OutT)r3;
  }
}

// ---------------------------------------------------------------------------
// accum3: final layer (no downstream argmin). f32 LUT -> f16 staged; packed
// v_pk_add_f16 inner loop, partials flushed to f32 every 8 codebooks.
// v8 staging: 4 lanes x float4 cover one LUT row's 16 useful cols (64B fully
// used, 16 segments/wave-load vs 32 before); each thread cvts 4 f32->f16 and
// ds_write_b64 at row*80 + c*8 bytes -> 8-lane group hits 4 quads, 2 lanes
// each merged within one 16B line = conflict-free. Rows 40 halfs (80B):
// gather bank-quad (5*idx+h)%8 bijective -> 2-way = free (unchanged).
// Index read: one lane-contiguous dwordx4 per chunk from transposed
// i3b[ch][p][16] (was stride-64 -> 64 req/wave).
// grid (49, 64), block 256 (4 waves): 128 positions x 16 channels.
// ---------------------------------------------------------------------------
__global__ __launch_bounds__(256) void accum3_f16(
    const float* __restrict__ lut, const uint8_t* __restrict__ i3b,
    const float* __restrict__ scale, const float* __restrict__ bias,
    const float* __restrict__ res, float* __restrict__ out) {
  __shared__ half_t s16[16 * 640];   // 20 KB
  const int t = threadIdx.x;
  const int lane = t & 63;
  const int wave = t >> 6;           // 0..3
  const int h = wave & 1;            // channel half (8 f16 ch)
  const int pg = wave >> 1;          // 0..1
  const int p = blockIdx.x * 128 + pg * 64 + lane;
  const int o_base = blockIdx.y * 16;
  // staging: slot s = t + 256j of 1024 -> row r = s>>2 (cb=r>>4, k=r&15),
  // col c = s&3 (floats 4c..4c+3 of the 16 useful cols)
  const int rs = t >> 2, cg = t & 3;
  const size_t cs = (size_t)16 * 16 * 1024;     // 16 cb per chunk (f32 elems)
  constexpr int NCHUNK = 4;
  float acc[8];
#pragma unroll
  for (int i = 0; i < 8; i++) acc[i] = 0.f;
  for (int ch = 0; ch < NCHUNK; ch++) {
    __syncthreads();
    const uint4 iw = *(const uint4*)(i3b + ((size_t)ch * BP + p) * 16);
    {
#pragma unroll
      for (int j = 0; j < 4; j++) {
        const int r = rs + 64 * j;
        const float4 v = *(const float4*)(lut + (size_t)ch * cs +
                                          (size_t)r * 1024 + o_base + cg * 4);
        half4v hv;
        hv[0] = (half_t)v.x; hv[1] = (half_t)v.y;
        hv[2] = (half_t)v.z; hv[3] = (half_t)v.w;
        *(half4v*)(s16 + (r >> 4) * 640 + (r & 15) * 40 + cg * 4) = hv;
      }
    }
    __syncthreads();
#pragma unroll
    for (int grp = 0; grp < 2; grp++) {   // 8 cb per f32 flush
      uint32_t wa = grp ? iw.z : iw.x;
      uint32_t wb = grp ? iw.w : iw.y;
      half2v p0 = 0, p1 = 0, p2 = 0, p3 = 0;
#pragma unroll
      for (int j = 0; j < 8; j++) {
        uint32_t w = (j < 4) ? wa : wb;
        int idx = (int)((w >> ((j & 3) * 8)) & 15u);
        int cb_l = grp * 8 + j;
        const half8v v = *(const half8v*)(s16 + cb_l * 640 + idx * 40 + h * 8);
        const half2v* vp = (const half2v*)&v;
        p0 += vp[0]; p1 += vp[1]; p2 += vp[2]; p3 += vp[3];
      }
      acc[0] += (float)p0[0]; acc[1] += (float)p0[1];
      acc[2] += (float)p1[0]; acc[3] += (float)p1[1];
      acc[4] += (float)p2[0]; acc[5] += (float)p2[1];
      acc[6] += (float)p3[0]; acc[7] += (float)p3[1];
    }
  }
  const unsigned b = (unsigned)p / 196u;
  const unsigned pr = (unsigned)p - b * 196u;
  const int o = o_base + h * 8;
  const float* rp = res + ((size_t)b * 1024 + o) * PP + pr;
  float* op = out + ((size_t)b * 1024 + o) * PP + pr;
#pragma unroll
  for (int i = 0; i < 8; i++) {
    float v = acc[i] * scale[o + i] + bias[o + i] + rp[(size_t)i * PP];
    op[(size_t)i * PP] = fmaxf(v, 0.f);
  }
}

// ---------------------------------------------------------------------------

extern "C" void kernel_launch(void* const* d_in, const int* in_sizes, int n_in,
                              void* d_out, int out_size, void* d_ws, size_t ws_size,
                              hipStream_t stream) {
  const float* x   = (const float*)d_in[0];   // [32,1024,14,14]
  const float* c1c = (const float*)d_in[1];
  const float* c1l = (const float*)d_in[2];
  const float* c1s = (const float*)d_in[3];
  const float* c1b = (const float*)d_in[4];
  const float* c2c = (const float*)d_in[5];
  const float* c2l = (const float*)d_in[6];
  const float* c2s = (const float*)d_in[7];
  const float* c2b = (const float*)d_in[8];
  const float* c3c = (const float*)d_in[9];
  const float* c3l = (const float*)d_in[10];  // [64,16,1024]
  const float* c3s = (const float*)d_in[11];
  const float* c3b = (const float*)d_in[12];

  const size_t sz_i1  = (size_t)32 * BP * 4;      // 802,816 B
  const size_t sz_i2  = (size_t)32 * BP * 4;
  const size_t sz_i3b = (size_t)BP * 64;          // 401,408 B (byte indices)
  const size_t sz_o64 = (size_t)BP * 256 * 8;     // 12.85 MB

  char* w = (char*)d_ws;
  uint32_t* i1 = (uint32_t*)w; w += sz_i1;
  uint32_t* i2 = (uint32_t*)w; w += sz_i2;
  uint8_t* i3b = (uint8_t*)w;  w += sz_i3b;
  double* out1;
  if (ws_size >= (size_t)(w - (char*)d_ws) + sz_o64) {
    out1 = (double*)w;
  } else {
    // d_out (25.69 MB f32) holds one 12.85 MB f64 array in its first half;
    // accum3 (final) reads only i3b/x/c3l, then overwrites all of d_out.
    out1 = (double*)d_out;
  }

  const dim3 blkA(256), blkC(256);
  // layer 1: 1x1, 256 codebooks (dsub=4) over 1024 input channels
  assign_1x1<float><<<dim3(25, 32), blkA, 0, stream>>>(x, c1c, i1, 1024);
  accum_f64<256, 256, true, false, double><<<dim3(98, 16), blkC, 0, stream>>>(
      c1l, i1, c1s, c1b, nullptr, nullptr, out1);
  // layer 2: 3x3, 256 codebooks (dsub=9); epilogue fuses the layer-3 assign
  assign_3x3<<<dim3(25, 32), blkA, 0, stream>>>(out1, c2c, i2);
  accum_f64<256, 256, true, true, double><<<dim3(98, 16), blkC, 0, stream>>>(
      c2l, i2, c2s, c2b, c3c, i3b, nullptr);
  // layer 3: 64 codebooks over 256 channels; fused residual + relu
  accum3_f16<<<dim3(49, 64), blkC, 0, stream>>>(
      c3l, i3b, c3s, c3b, x, (float*)d_out);
}